// Round 1
// 10886.525 us; speedup vs baseline: 2.5621x; 2.5621x over previous
//
#include <hip/hip_runtime.h>
#include <hip/hip_bf16.h>
#include <math.h>

#define D_MODEL 512
#define N_HEADS 8
#define D_HEAD 64
#define N_LAYERS 6
#define D_FF 2048
#define VOCAB 50257
#define ENC_LEN 2048
#define DEC_LEN 1024

// ---------------------------------------------------------------------------
// Embedding lookup + sinusoidal positional encoding
// grid: (S), block: (512) -- one thread per feature dim
// ---------------------------------------------------------------------------
__global__ __launch_bounds__(512) void embed_pe_kernel(
    const int* __restrict__ ids, const float* __restrict__ dict,
    float* __restrict__ out) {
  int s = blockIdx.x;
  int d = threadIdx.x;
  float v = dict[(long)ids[s] * D_MODEL + d];
  float expo = (float)(d & ~1) / (float)D_MODEL;
  // 10000^(-expo) = exp(-expo * ln(10000))
  float ang = (float)s * expf(-expo * 9.210340371976184f);
  v += (d & 1) ? cosf(ang) : sinf(ang);
  out[(long)s * D_MODEL + d] = v;
}

// ---------------------------------------------------------------------------
// Tiled fp32 GEMM: C[M,N] = A[M,K] @ B[K,N]   (optionally ReLU)
// M multiple of 64, K multiple of 16, N arbitrary (guarded).
// 64x64 tile, BK=16, 256 threads, 4x4 micro-tile per thread.
// LDS laid out so compute reads are float4 (ds_read_b128).
// ---------------------------------------------------------------------------
template <int RELU>
__global__ __launch_bounds__(256) void gemm_kernel(
    const float* __restrict__ A, int lda,
    const float* __restrict__ B, int ldb,
    float* __restrict__ C, int ldc,
    int N, int K) {
  __shared__ float As[16][68];  // [k][m], padded
  __shared__ float Bs[16][64];  // [k][n]

  const int bn = blockIdx.x, bm = blockIdx.y;
  const int tid = threadIdx.x;
  const int tx = tid & 15;       // 0..15 -> col group
  const int ty = tid >> 4;       // 0..15 -> row group

  // A tile load mapping: each thread one float4 along k
  const int arow = tid >> 2;          // 0..63
  const int acol4 = (tid & 3) * 4;    // 0,4,8,12
  const float* Abase = A + (long)(bm * 64 + arow) * lda + acol4;

  // B tile load mapping: 16 rows x 64 cols, scalar guarded loads
  const int br = tid >> 4;   // 0..15 (k row)
  const int bc = tid & 15;   // 0..15 (col base, +j*16)

  float acc[4][4];
#pragma unroll
  for (int i = 0; i < 4; ++i)
#pragma unroll
    for (int j = 0; j < 4; ++j) acc[i][j] = 0.0f;

  for (int k0 = 0; k0 < K; k0 += 16) {
    // --- load A 64x16 ---
    float4 av = *(const float4*)(Abase + k0);
    As[acol4 + 0][arow] = av.x;
    As[acol4 + 1][arow] = av.y;
    As[acol4 + 2][arow] = av.z;
    As[acol4 + 3][arow] = av.w;
    // --- load B 16x64 (guarded on N) ---
    {
      const float* Bp = B + (long)(k0 + br) * ldb + bn * 64 + bc;
#pragma unroll
      for (int j = 0; j < 4; ++j) {
        int col = bn * 64 + bc + j * 16;
        Bs[br][bc + j * 16] = (col < N) ? Bp[j * 16] : 0.0f;
      }
    }
    __syncthreads();
#pragma unroll
    for (int kk = 0; kk < 16; ++kk) {
      float4 a = *(const float4*)&As[kk][ty * 4];
      float4 b = *(const float4*)&Bs[kk][tx * 4];
      acc[0][0] += a.x * b.x; acc[0][1] += a.x * b.y;
      acc[0][2] += a.x * b.z; acc[0][3] += a.x * b.w;
      acc[1][0] += a.y * b.x; acc[1][1] += a.y * b.y;
      acc[1][2] += a.y * b.z; acc[1][3] += a.y * b.w;
      acc[2][0] += a.z * b.x; acc[2][1] += a.z * b.y;
      acc[2][2] += a.z * b.z; acc[2][3] += a.z * b.w;
      acc[3][0] += a.w * b.x; acc[3][1] += a.w * b.y;
      acc[3][2] += a.w * b.z; acc[3][3] += a.w * b.w;
    }
    __syncthreads();
  }

#pragma unroll
  for (int i = 0; i < 4; ++i) {
    int row = bm * 64 + ty * 4 + i;
    float* Cp = C + (long)row * ldc + bn * 64 + tx * 4;
#pragma unroll
    for (int j = 0; j < 4; ++j) {
      int col = bn * 64 + tx * 4 + j;
      if (col < N) {
        float v = acc[i][j];
        if (RELU) v = fmaxf(v, 0.0f);
        Cp[j] = v;
      }
    }
  }
}

// ---------------------------------------------------------------------------
// Flash-style fused attention, fp32.
// One block = 64 query rows x 1 head.  256 threads = 16x16, 4x4 micro-tile.
// Per K-tile (64 keys):
//   - stage K-tile transposed [d][k] in LDS, S = (Q*scale) K^T  (64x64x64 GEMM)
//   - causal mask (diag tile only), online softmax (m,l in regs, replicated
//     across the 16-lane row group via shfl_xor), P -> LDS [q][k]
//   - re-stage same LDS buffer with V-tile [k][d], O += P V  (64x64x64 GEMM)
// Sq, Sk multiples of 64 (2048 / 1024 here).
// grid: (Sq/64, H)
// ---------------------------------------------------------------------------
template <int CAUSAL>
__global__ __launch_bounds__(256) void flash_attn_kernel(
    const float* __restrict__ Q, int ldq,
    const float* __restrict__ K, int ldk,
    const float* __restrict__ V, int ldv,
    float* __restrict__ O, int ldo,
    int Sk) {
  __shared__ float Qs[64][68];     // [d][q]  (transposed, pre-scaled)
  __shared__ float KV[64 * 68];    // K-tile as [d][k] stride 68, then V-tile as [k][d] stride 64
  __shared__ float Ps[64][68];     // [q][k]

  const int qt = blockIdx.x;
  const int h = blockIdx.y;
  const int tid = threadIdx.x;
  const int tx = tid & 15;   // k-col group
  const int ty = tid >> 4;   // q-row group

  const int lrow = tid >> 2;       // 0..63 (row for staging)
  const int lq = tid & 3;          // quad selector (16 floats per thread)

  // ---- load Q tile (transpose + pre-scale by 1/sqrt(64)) ----
  {
    const float* Qp = Q + (long)(qt * 64 + lrow) * ldq + h * D_HEAD + lq * 16;
#pragma unroll
    for (int f = 0; f < 4; ++f) {
      float4 v = *(const float4*)(Qp + f * 4);
      int d0 = lq * 16 + f * 4;
      Qs[d0 + 0][lrow] = v.x * 0.125f;
      Qs[d0 + 1][lrow] = v.y * 0.125f;
      Qs[d0 + 2][lrow] = v.z * 0.125f;
      Qs[d0 + 3][lrow] = v.w * 0.125f;
    }
  }

  float m[4], l[4], o[4][4];
#pragma unroll
  for (int i = 0; i < 4; ++i) {
    m[i] = -1e30f;
    l[i] = 0.0f;
#pragma unroll
    for (int j = 0; j < 4; ++j) o[i][j] = 0.0f;
  }
  __syncthreads();

  const int nkt = CAUSAL ? (qt + 1) : (Sk >> 6);
  for (int kt = 0; kt < nkt; ++kt) {
    // ---- stage K tile transposed: KV[d][k], stride 68 ----
    {
      const float* Kp = K + (long)(kt * 64 + lrow) * ldk + h * D_HEAD + lq * 16;
#pragma unroll
      for (int f = 0; f < 4; ++f) {
        float4 v = *(const float4*)(Kp + f * 4);
        int d0 = lq * 16 + f * 4;
        KV[(d0 + 0) * 68 + lrow] = v.x;
        KV[(d0 + 1) * 68 + lrow] = v.y;
        KV[(d0 + 2) * 68 + lrow] = v.z;
        KV[(d0 + 3) * 68 + lrow] = v.w;
      }
    }
    __syncthreads();

    // ---- S = (Q*scale) K^T ----
    float s[4][4];
#pragma unroll
    for (int i = 0; i < 4; ++i)
#pragma unroll
      for (int j = 0; j < 4; ++j) s[i][j] = 0.0f;
#pragma unroll 8
    for (int kk = 0; kk < 64; ++kk) {
      float4 a = *(const float4*)&Qs[kk][ty * 4];
      float4 b = *(const float4*)&KV[kk * 68 + tx * 4];
      s[0][0] += a.x * b.x; s[0][1] += a.x * b.y;
      s[0][2] += a.x * b.z; s[0][3] += a.x * b.w;
      s[1][0] += a.y * b.x; s[1][1] += a.y * b.y;
      s[1][2] += a.y * b.z; s[1][3] += a.y * b.w;
      s[2][0] += a.z * b.x; s[2][1] += a.z * b.y;
      s[2][2] += a.z * b.z; s[2][3] += a.z * b.w;
      s[3][0] += a.w * b.x; s[3][1] += a.w * b.y;
      s[3][2] += a.w * b.z; s[3][3] += a.w * b.w;
    }

    // ---- causal mask (only the diagonal tile is partial) ----
    if (CAUSAL && kt == qt) {
#pragma unroll
      for (int i = 0; i < 4; ++i)
#pragma unroll
        for (int j = 0; j < 4; ++j)
          if (tx * 4 + j > ty * 4 + i) s[i][j] = -1e30f;
    }

    // ---- online softmax update; write P to LDS [q][k] ----
#pragma unroll
    for (int i = 0; i < 4; ++i) {
      float rm = fmaxf(fmaxf(s[i][0], s[i][1]), fmaxf(s[i][2], s[i][3]));
#pragma unroll
      for (int off = 1; off < 16; off <<= 1)
        rm = fmaxf(rm, __shfl_xor(rm, off));
      float mn = fmaxf(m[i], rm);
      float sc = __expf(m[i] - mn);
      float p0 = __expf(s[i][0] - mn);
      float p1 = __expf(s[i][1] - mn);
      float p2 = __expf(s[i][2] - mn);
      float p3 = __expf(s[i][3] - mn);
      float rs = (p0 + p1) + (p2 + p3);
#pragma unroll
      for (int off = 1; off < 16; off <<= 1) rs += __shfl_xor(rs, off);
      l[i] = l[i] * sc + rs;
      m[i] = mn;
      o[i][0] *= sc; o[i][1] *= sc; o[i][2] *= sc; o[i][3] *= sc;
      float4 pv = make_float4(p0, p1, p2, p3);
      *(float4*)&Ps[ty * 4 + i][tx * 4] = pv;
    }
    __syncthreads();  // Ps visible; all K-tile reads done before V overwrite

    // ---- stage V tile natural: KV[k][d], stride 64 ----
    {
      const float* Vp = V + (long)(kt * 64 + lrow) * ldv + h * D_HEAD + lq * 16;
#pragma unroll
      for (int f = 0; f < 4; ++f) {
        float4 v = *(const float4*)(Vp + f * 4);
        *(float4*)&KV[lrow * 64 + lq * 16 + f * 4] = v;
      }
    }
    __syncthreads();

    // ---- O += P V ----
#pragma unroll 4
    for (int kk0 = 0; kk0 < 64; kk0 += 4) {
      float a[4][4];
#pragma unroll
      for (int i = 0; i < 4; ++i)
        *(float4*)a[i] = *(const float4*)&Ps[ty * 4 + i][kk0];
#pragma unroll
      for (int u = 0; u < 4; ++u) {
        float4 b = *(const float4*)&KV[(kk0 + u) * 64 + tx * 4];
        o[0][0] += a[0][u] * b.x; o[0][1] += a[0][u] * b.y;
        o[0][2] += a[0][u] * b.z; o[0][3] += a[0][u] * b.w;
        o[1][0] += a[1][u] * b.x; o[1][1] += a[1][u] * b.y;
        o[1][2] += a[1][u] * b.z; o[1][3] += a[1][u] * b.w;
        o[2][0] += a[2][u] * b.x; o[2][1] += a[2][u] * b.y;
        o[2][2] += a[2][u] * b.z; o[2][3] += a[2][u] * b.w;
        o[3][0] += a[3][u] * b.x; o[3][1] += a[3][u] * b.y;
        o[3][2] += a[3][u] * b.z; o[3][3] += a[3][u] * b.w;
      }
    }
    __syncthreads();  // protect KV/Ps before next tile
  }

  // ---- epilogue: O / l ----
#pragma unroll
  for (int i = 0; i < 4; ++i) {
    float inv = 1.0f / l[i];
    float* Op = O + (long)(qt * 64 + ty * 4 + i) * ldo + h * D_HEAD + tx * 4;
    float4 ov = make_float4(o[i][0] * inv, o[i][1] * inv, o[i][2] * inv,
                            o[i][3] * inv);
    *(float4*)Op = ov;
  }
}

// ---------------------------------------------------------------------------
// x = layernorm(x + y)  (no affine, eps=1e-6), rows of 512
// grid: (S), block: 256 (2 elements per thread)
// ---------------------------------------------------------------------------
__global__ __launch_bounds__(256) void add_norm_kernel(
    float* __restrict__ x, const float* __restrict__ y) {
  __shared__ float red[4];
  const int row = blockIdx.x;
  const int tid = threadIdx.x;
  float* xr = x + (long)row * D_MODEL;
  const float* yr = y + (long)row * D_MODEL;

  float v0 = xr[tid] + yr[tid];
  float v1 = xr[tid + 256] + yr[tid + 256];

  float s = v0 + v1;
#pragma unroll
  for (int off = 1; off < 64; off <<= 1) s += __shfl_xor(s, off);
  if ((tid & 63) == 0) red[tid >> 6] = s;
  __syncthreads();
  const float mean = (red[0] + red[1] + red[2] + red[3]) * (1.0f / D_MODEL);

  float d0 = v0 - mean, d1 = v1 - mean;
  float vs = d0 * d0 + d1 * d1;
#pragma unroll
  for (int off = 1; off < 64; off <<= 1) vs += __shfl_xor(vs, off);
  __syncthreads();  // protect mean reads
  if ((tid & 63) == 0) red[tid >> 6] = vs;
  __syncthreads();
  const float var = (red[0] + red[1] + red[2] + red[3]) * (1.0f / D_MODEL);
  const float rn = rsqrtf(var + 1e-6f);
  xr[tid] = d0 * rn;
  xr[tid + 256] = d1 * rn;
}

// ---------------------------------------------------------------------------
extern "C" void kernel_launch(void* const* d_in, const int* in_sizes, int n_in,
                              void* d_out, int out_size, void* d_ws, size_t ws_size,
                              hipStream_t stream) {
  const int* input_ids   = (const int*)d_in[0];
  const int* dec_ids     = (const int*)d_in[1];
  const float* dict      = (const float*)d_in[2];
  const float* mh_input  = (const float*)d_in[3];
  const float* wo_input  = (const float*)d_in[4];
  const float* mh_masked = (const float*)d_in[5];
  const float* wo_masked = (const float*)d_in[6];
  const float* mh_output = (const float*)d_in[7];
  const float* wo_output = (const float*)d_in[8];
  const float* ff_in_w1  = (const float*)d_in[9];
  const float* ff_in_w2  = (const float*)d_in[10];
  const float* ff_out_w1 = (const float*)d_in[11];
  const float* ff_out_w2 = (const float*)d_in[12];
  const float* last_lin  = (const float*)d_in[13];
  float* out = (float*)d_out;

  // workspace layout (floats); total ~11.01M floats = ~44 MB
  float* ws  = (float*)d_ws;
  float* enc = ws;                              // 2048*512
  float* dec = enc + ENC_LEN * D_MODEL;         // 1024*512
  float* qkv = dec + DEC_LEN * D_MODEL;         // 2048*1536 region
  float* att = qkv + (long)ENC_LEN * 3 * D_MODEL;  // 2048*512
  float* prj = att + ENC_LEN * D_MODEL;         // 2048*512
  float* hid = prj + ENC_LEN * D_MODEL;         // 2048*2048

  auto gemm = [&](const float* A, int lda, const float* B, int ldb,
                  float* C, int ldc, int M, int N, int K, bool relu) {
    dim3 g((N + 63) / 64, M / 64), b(256);
    if (relu)
      gemm_kernel<1><<<g, b, 0, stream>>>(A, lda, B, ldb, C, ldc, N, K);
    else
      gemm_kernel<0><<<g, b, 0, stream>>>(A, lda, B, ldb, C, ldc, N, K);
  };

  // ===== Encoder =====
  embed_pe_kernel<<<ENC_LEN, D_MODEL, 0, stream>>>(input_ids, dict, enc);
  for (int l = 0; l < N_LAYERS; ++l) {
    const float* W = mh_input + (long)l * D_MODEL * 3 * D_MODEL;
    gemm(enc, D_MODEL, W, 3 * D_MODEL, qkv, 3 * D_MODEL,
         ENC_LEN, 3 * D_MODEL, D_MODEL, false);
    flash_attn_kernel<0><<<dim3(ENC_LEN / 64, N_HEADS), 256, 0, stream>>>(
        qkv, 3 * D_MODEL, qkv + D_MODEL, 3 * D_MODEL, qkv + 2 * D_MODEL,
        3 * D_MODEL, att, D_MODEL, ENC_LEN);
    gemm(att, D_MODEL, wo_input + (long)l * D_MODEL * D_MODEL, D_MODEL,
         prj, D_MODEL, ENC_LEN, D_MODEL, D_MODEL, false);
    add_norm_kernel<<<ENC_LEN, 256, 0, stream>>>(enc, prj);
    gemm(enc, D_MODEL, ff_in_w1 + (long)l * D_MODEL * D_FF, D_FF,
         hid, D_FF, ENC_LEN, D_FF, D_MODEL, true);
    gemm(hid, D_FF, ff_in_w2 + (long)l * D_FF * D_MODEL, D_MODEL,
         prj, D_MODEL, ENC_LEN, D_MODEL, D_FF, false);
    add_norm_kernel<<<ENC_LEN, 256, 0, stream>>>(enc, prj);
  }

  // ===== Decoder =====
  embed_pe_kernel<<<DEC_LEN, D_MODEL, 0, stream>>>(dec_ids, dict, dec);
  float* qb = qkv;                        // 1024*512
  float* kb = qkv + DEC_LEN * D_MODEL;    // 2048*512
  float* vb = kb + ENC_LEN * D_MODEL;     // 2048*512
  for (int l = 0; l < N_LAYERS; ++l) {
    // masked self-attention
    const float* Wm = mh_masked + (long)l * D_MODEL * 3 * D_MODEL;
    gemm(dec, D_MODEL, Wm, 3 * D_MODEL, qkv, 3 * D_MODEL,
         DEC_LEN, 3 * D_MODEL, D_MODEL, false);
    flash_attn_kernel<1><<<dim3(DEC_LEN / 64, N_HEADS), 256, 0, stream>>>(
        qkv, 3 * D_MODEL, qkv + D_MODEL, 3 * D_MODEL, qkv + 2 * D_MODEL,
        3 * D_MODEL, att, D_MODEL, DEC_LEN);
    gemm(att, D_MODEL, wo_masked + (long)l * D_MODEL * D_MODEL, D_MODEL,
         prj, D_MODEL, DEC_LEN, D_MODEL, D_MODEL, false);
    add_norm_kernel<<<DEC_LEN, 256, 0, stream>>>(dec, prj);
    // cross-attention (q from dec, k/v from enc)
    const float* Wc = mh_output + (long)l * D_MODEL * 3 * D_MODEL;
    gemm(dec, D_MODEL, Wc, 3 * D_MODEL, qb, D_MODEL,
         DEC_LEN, D_MODEL, D_MODEL, false);
    gemm(enc, D_MODEL, Wc + D_MODEL, 3 * D_MODEL, kb, D_MODEL,
         ENC_LEN, D_MODEL, D_MODEL, false);
    gemm(enc, D_MODEL, Wc + 2 * D_MODEL, 3 * D_MODEL, vb, D_MODEL,
         ENC_LEN, D_MODEL, D_MODEL, false);
    flash_attn_kernel<0><<<dim3(DEC_LEN / 64, N_HEADS), 256, 0, stream>>>(
        qb, D_MODEL, kb, D_MODEL, vb, D_MODEL, att, D_MODEL, ENC_LEN);
    gemm(att, D_MODEL, wo_output + (long)l * D_MODEL * D_MODEL, D_MODEL,
         prj, D_MODEL, DEC_LEN, D_MODEL, D_MODEL, false);
    add_norm_kernel<<<DEC_LEN, 256, 0, stream>>>(dec, prj);
    // FFN
    gemm(dec, D_MODEL, ff_out_w1 + (long)l * D_MODEL * D_FF, D_FF,
         hid, D_FF, DEC_LEN, D_FF, D_MODEL, true);
    gemm(hid, D_FF, ff_out_w2 + (long)l * D_FF * D_MODEL, D_MODEL,
         prj, D_MODEL, DEC_LEN, D_MODEL, D_FF, false);
    add_norm_kernel<<<DEC_LEN, 256, 0, stream>>>(dec, prj);
  }

  // ===== Final projection to vocab =====
  gemm(dec, D_MODEL, last_lin, VOCAB, out, VOCAB, DEC_LEN, VOCAB, D_MODEL, false);
}

// Round 2
// 10399.295 us; speedup vs baseline: 2.6822x; 1.0469x over previous
//
#include <hip/hip_runtime.h>
#include <hip/hip_bf16.h>
#include <math.h>

#define D_MODEL 512
#define N_HEADS 8
#define D_HEAD 64
#define N_LAYERS 6
#define D_FF 2048
#define VOCAB 50257
#define ENC_LEN 2048
#define DEC_LEN 1024

// ---------------------------------------------------------------------------
// Embedding lookup + sinusoidal positional encoding
// ---------------------------------------------------------------------------
__global__ __launch_bounds__(512) void embed_pe_kernel(
    const int* __restrict__ ids, const float* __restrict__ dict,
    float* __restrict__ out) {
  int s = blockIdx.x;
  int d = threadIdx.x;
  float v = dict[(long)ids[s] * D_MODEL + d];
  float expo = (float)(d & ~1) / (float)D_MODEL;
  float ang = (float)s * expf(-expo * 9.210340371976184f);
  v += (d & 1) ? cosf(ang) : sinf(ang);
  out[(long)s * D_MODEL + d] = v;
}

// ---------------------------------------------------------------------------
// 64x64-tile fp32 GEMM (mid-size shapes). 256 thr, 4x4 micro, BK=16.
// Bs padded to 68 to kill the 4-way store bank conflict.
// ---------------------------------------------------------------------------
template <int RELU>
__global__ __launch_bounds__(256) void gemm_kernel(
    const float* __restrict__ A, int lda,
    const float* __restrict__ B, int ldb,
    float* __restrict__ C, int ldc,
    int N, int K) {
  __shared__ float As[16][68];  // [k][m], padded
  __shared__ float Bs[16][68];  // [k][n], padded (bank-conflict fix)

  const int bn = blockIdx.x, bm = blockIdx.y;
  const int tid = threadIdx.x;
  const int tx = tid & 15;
  const int ty = tid >> 4;

  const int arow = tid >> 2;
  const int acol4 = (tid & 3) * 4;
  const float* Abase = A + (long)(bm * 64 + arow) * lda + acol4;

  const int br = tid >> 4;
  const int bc = tid & 15;

  float acc[4][4];
#pragma unroll
  for (int i = 0; i < 4; ++i)
#pragma unroll
    for (int j = 0; j < 4; ++j) acc[i][j] = 0.0f;

  for (int k0 = 0; k0 < K; k0 += 16) {
    float4 av = *(const float4*)(Abase + k0);
    As[acol4 + 0][arow] = av.x;
    As[acol4 + 1][arow] = av.y;
    As[acol4 + 2][arow] = av.z;
    As[acol4 + 3][arow] = av.w;
    {
      const float* Bp = B + (long)(k0 + br) * ldb + bn * 64 + bc;
#pragma unroll
      for (int j = 0; j < 4; ++j) {
        int col = bn * 64 + bc + j * 16;
        Bs[br][bc + j * 16] = (col < N) ? Bp[j * 16] : 0.0f;
      }
    }
    __syncthreads();
#pragma unroll
    for (int kk = 0; kk < 16; ++kk) {
      float4 a = *(const float4*)&As[kk][ty * 4];
      float4 b = *(const float4*)&Bs[kk][tx * 4];
      acc[0][0] += a.x * b.x; acc[0][1] += a.x * b.y;
      acc[0][2] += a.x * b.z; acc[0][3] += a.x * b.w;
      acc[1][0] += a.y * b.x; acc[1][1] += a.y * b.y;
      acc[1][2] += a.y * b.z; acc[1][3] += a.y * b.w;
      acc[2][0] += a.z * b.x; acc[2][1] += a.z * b.y;
      acc[2][2] += a.z * b.z; acc[2][3] += a.z * b.w;
      acc[3][0] += a.w * b.x; acc[3][1] += a.w * b.y;
      acc[3][2] += a.w * b.z; acc[3][3] += a.w * b.w;
    }
    __syncthreads();
  }

#pragma unroll
  for (int i = 0; i < 4; ++i) {
    int row = bm * 64 + ty * 4 + i;
    float* Cp = C + (long)row * ldc + bn * 64 + tx * 4;
#pragma unroll
    for (int j = 0; j < 4; ++j) {
      int col = bn * 64 + tx * 4 + j;
      if (col < N) {
        float v = acc[i][j];
        if (RELU) v = fmaxf(v, 0.0f);
        Cp[j] = v;
      }
    }
  }
}

// ---------------------------------------------------------------------------
// 128x128-tile fp32 GEMM (large shapes). 256 thr, 8x8 micro, BK=16.
// LDS 1 B/FLOP (half of 64-tile) -> VALU-limited ~110 TF.
// grid: (M/128, ceil(N/128), batch)  -- bm fastest so consecutive blocks
// share the B panel (L2/L3 reuse; B is the big operand in vocab GEMM).
// Optional batching via strideB/strideC (A shared across batch).
// ---------------------------------------------------------------------------
template <int RELU>
__global__ __launch_bounds__(256, 2) void gemm128_kernel(
    const float* __restrict__ A, int lda,
    const float* __restrict__ B, int ldb,
    float* __restrict__ C, int ldc,
    int N, int K, long strideB, long strideC) {
  __shared__ float As[16][132];  // [k][m]
  __shared__ float Bs[16][132];  // [k][n]

  const int bm = blockIdx.x, bn = blockIdx.y;
  const int z = blockIdx.z;
  const float* Bb = B + (long)z * strideB;
  float* Cb = C + (long)z * strideC;

  const int tid = threadIdx.x;
  const int tx = tid & 15;
  const int ty = tid >> 4;
  const bool fullN = (bn * 128 + 128 <= N);

  float acc[8][8];
#pragma unroll
  for (int i = 0; i < 8; ++i)
#pragma unroll
    for (int j = 0; j < 8; ++j) acc[i][j] = 0.0f;

  for (int k0 = 0; k0 < K; k0 += 16) {
    // --- A tile 128x16: 512 float4, 2 per thread ---
#pragma unroll
    for (int r = 0; r < 2; ++r) {
      int idx = r * 256 + tid;
      int m = idx >> 2;
      int kq = (idx & 3) * 4;
      float4 v = *(const float4*)(A + (long)(bm * 128 + m) * lda + k0 + kq);
      As[kq + 0][m] = v.x;
      As[kq + 1][m] = v.y;
      As[kq + 2][m] = v.z;
      As[kq + 3][m] = v.w;
    }
    // --- B tile 16x128: 512 float4, 2 per thread ---
#pragma unroll
    for (int r = 0; r < 2; ++r) {
      int idx = r * 256 + tid;
      int kk = idx >> 5;
      int nq = (idx & 31) * 4;
      int col = bn * 128 + nq;
      const float* Bp = Bb + (long)(k0 + kk) * ldb + col;
      if (fullN) {
        float4 v = *(const float4*)Bp;
        *(float4*)&Bs[kk][nq] = v;
      } else {
#pragma unroll
        for (int j = 0; j < 4; ++j)
          Bs[kk][nq + j] = (col + j < N) ? Bp[j] : 0.0f;
      }
    }
    __syncthreads();
#pragma unroll
    for (int kk = 0; kk < 16; ++kk) {
      float a8[8], b8[8];
      *(float4*)&a8[0] = *(const float4*)&As[kk][ty * 4];
      *(float4*)&a8[4] = *(const float4*)&As[kk][64 + ty * 4];
      *(float4*)&b8[0] = *(const float4*)&Bs[kk][tx * 4];
      *(float4*)&b8[4] = *(const float4*)&Bs[kk][64 + tx * 4];
#pragma unroll
      for (int i = 0; i < 8; ++i)
#pragma unroll
        for (int j = 0; j < 8; ++j) acc[i][j] += a8[i] * b8[j];
    }
    __syncthreads();
  }

#pragma unroll
  for (int ih = 0; ih < 2; ++ih) {
#pragma unroll
    for (int i = 0; i < 4; ++i) {
      int row = bm * 128 + ih * 64 + ty * 4 + i;
      float* Cp = Cb + (long)row * ldc + bn * 128;
#pragma unroll
      for (int jh = 0; jh < 2; ++jh) {
        int c0 = jh * 64 + tx * 4;
        float v0 = acc[ih * 4 + i][jh * 4 + 0];
        float v1 = acc[ih * 4 + i][jh * 4 + 1];
        float v2 = acc[ih * 4 + i][jh * 4 + 2];
        float v3 = acc[ih * 4 + i][jh * 4 + 3];
        if (RELU) {
          v0 = fmaxf(v0, 0.0f); v1 = fmaxf(v1, 0.0f);
          v2 = fmaxf(v2, 0.0f); v3 = fmaxf(v3, 0.0f);
        }
        if (fullN) {
          *(float4*)(Cp + c0) = make_float4(v0, v1, v2, v3);
        } else {
          int col = bn * 128 + c0;
          if (col + 0 < N) Cp[c0 + 0] = v0;
          if (col + 1 < N) Cp[c0 + 1] = v1;
          if (col + 2 < N) Cp[c0 + 2] = v2;
          if (col + 3 < N) Cp[c0 + 3] = v3;
        }
      }
    }
  }
}

// ---------------------------------------------------------------------------
// Flash-style fused attention, fp32 (unchanged from R1).
// ---------------------------------------------------------------------------
template <int CAUSAL>
__global__ __launch_bounds__(256) void flash_attn_kernel(
    const float* __restrict__ Q, int ldq,
    const float* __restrict__ K, int ldk,
    const float* __restrict__ V, int ldv,
    float* __restrict__ O, int ldo,
    int Sk) {
  __shared__ float Qs[64][68];     // [d][q]  (transposed, pre-scaled)
  __shared__ float KV[64 * 68];    // K-tile [d][k] stride 68, then V-tile [k][d] stride 64
  __shared__ float Ps[64][68];     // [q][k]

  const int qt = blockIdx.x;
  const int h = blockIdx.y;
  const int tid = threadIdx.x;
  const int tx = tid & 15;
  const int ty = tid >> 4;

  const int lrow = tid >> 2;
  const int lq = tid & 3;

  {
    const float* Qp = Q + (long)(qt * 64 + lrow) * ldq + h * D_HEAD + lq * 16;
#pragma unroll
    for (int f = 0; f < 4; ++f) {
      float4 v = *(const float4*)(Qp + f * 4);
      int d0 = lq * 16 + f * 4;
      Qs[d0 + 0][lrow] = v.x * 0.125f;
      Qs[d0 + 1][lrow] = v.y * 0.125f;
      Qs[d0 + 2][lrow] = v.z * 0.125f;
      Qs[d0 + 3][lrow] = v.w * 0.125f;
    }
  }

  float m[4], l[4], o[4][4];
#pragma unroll
  for (int i = 0; i < 4; ++i) {
    m[i] = -1e30f;
    l[i] = 0.0f;
#pragma unroll
    for (int j = 0; j < 4; ++j) o[i][j] = 0.0f;
  }
  __syncthreads();

  const int nkt = CAUSAL ? (qt + 1) : (Sk >> 6);
  for (int kt = 0; kt < nkt; ++kt) {
    {
      const float* Kp = K + (long)(kt * 64 + lrow) * ldk + h * D_HEAD + lq * 16;
#pragma unroll
      for (int f = 0; f < 4; ++f) {
        float4 v = *(const float4*)(Kp + f * 4);
        int d0 = lq * 16 + f * 4;
        KV[(d0 + 0) * 68 + lrow] = v.x;
        KV[(d0 + 1) * 68 + lrow] = v.y;
        KV[(d0 + 2) * 68 + lrow] = v.z;
        KV[(d0 + 3) * 68 + lrow] = v.w;
      }
    }
    __syncthreads();

    float s[4][4];
#pragma unroll
    for (int i = 0; i < 4; ++i)
#pragma unroll
      for (int j = 0; j < 4; ++j) s[i][j] = 0.0f;
#pragma unroll 8
    for (int kk = 0; kk < 64; ++kk) {
      float4 a = *(const float4*)&Qs[kk][ty * 4];
      float4 b = *(const float4*)&KV[kk * 68 + tx * 4];
      s[0][0] += a.x * b.x; s[0][1] += a.x * b.y;
      s[0][2] += a.x * b.z; s[0][3] += a.x * b.w;
      s[1][0] += a.y * b.x; s[1][1] += a.y * b.y;
      s[1][2] += a.y * b.z; s[1][3] += a.y * b.w;
      s[2][0] += a.z * b.x; s[2][1] += a.z * b.y;
      s[2][2] += a.z * b.z; s[2][3] += a.z * b.w;
      s[3][0] += a.w * b.x; s[3][1] += a.w * b.y;
      s[3][2] += a.w * b.z; s[3][3] += a.w * b.w;
    }

    if (CAUSAL && kt == qt) {
#pragma unroll
      for (int i = 0; i < 4; ++i)
#pragma unroll
        for (int j = 0; j < 4; ++j)
          if (tx * 4 + j > ty * 4 + i) s[i][j] = -1e30f;
    }

#pragma unroll
    for (int i = 0; i < 4; ++i) {
      float rm = fmaxf(fmaxf(s[i][0], s[i][1]), fmaxf(s[i][2], s[i][3]));
#pragma unroll
      for (int off = 1; off < 16; off <<= 1)
        rm = fmaxf(rm, __shfl_xor(rm, off));
      float mn = fmaxf(m[i], rm);
      float sc = __expf(m[i] - mn);
      float p0 = __expf(s[i][0] - mn);
      float p1 = __expf(s[i][1] - mn);
      float p2 = __expf(s[i][2] - mn);
      float p3 = __expf(s[i][3] - mn);
      float rs = (p0 + p1) + (p2 + p3);
#pragma unroll
      for (int off = 1; off < 16; off <<= 1) rs += __shfl_xor(rs, off);
      l[i] = l[i] * sc + rs;
      m[i] = mn;
      o[i][0] *= sc; o[i][1] *= sc; o[i][2] *= sc; o[i][3] *= sc;
      float4 pv = make_float4(p0, p1, p2, p3);
      *(float4*)&Ps[ty * 4 + i][tx * 4] = pv;
    }
    __syncthreads();

    {
      const float* Vp = V + (long)(kt * 64 + lrow) * ldv + h * D_HEAD + lq * 16;
#pragma unroll
      for (int f = 0; f < 4; ++f) {
        float4 v = *(const float4*)(Vp + f * 4);
        *(float4*)&KV[lrow * 64 + lq * 16 + f * 4] = v;
      }
    }
    __syncthreads();

#pragma unroll 4
    for (int kk0 = 0; kk0 < 64; kk0 += 4) {
      float a[4][4];
#pragma unroll
      for (int i = 0; i < 4; ++i)
        *(float4*)a[i] = *(const float4*)&Ps[ty * 4 + i][kk0];
#pragma unroll
      for (int u = 0; u < 4; ++u) {
        float4 b = *(const float4*)&KV[(kk0 + u) * 64 + tx * 4];
        o[0][0] += a[0][u] * b.x; o[0][1] += a[0][u] * b.y;
        o[0][2] += a[0][u] * b.z; o[0][3] += a[0][u] * b.w;
        o[1][0] += a[1][u] * b.x; o[1][1] += a[1][u] * b.y;
        o[1][2] += a[1][u] * b.z; o[1][3] += a[1][u] * b.w;
        o[2][0] += a[2][u] * b.x; o[2][1] += a[2][u] * b.y;
        o[2][2] += a[2][u] * b.z; o[2][3] += a[2][u] * b.w;
        o[3][0] += a[3][u] * b.x; o[3][1] += a[3][u] * b.y;
        o[3][2] += a[3][u] * b.z; o[3][3] += a[3][u] * b.w;
      }
    }
    __syncthreads();
  }

#pragma unroll
  for (int i = 0; i < 4; ++i) {
    float inv = 1.0f / l[i];
    float* Op = O + (long)(qt * 64 + ty * 4 + i) * ldo + h * D_HEAD + tx * 4;
    float4 ov = make_float4(o[i][0] * inv, o[i][1] * inv, o[i][2] * inv,
                            o[i][3] * inv);
    *(float4*)Op = ov;
  }
}

// ---------------------------------------------------------------------------
// x = layernorm(x + y)
// ---------------------------------------------------------------------------
__global__ __launch_bounds__(256) void add_norm_kernel(
    float* __restrict__ x, const float* __restrict__ y) {
  __shared__ float red[4];
  const int row = blockIdx.x;
  const int tid = threadIdx.x;
  float* xr = x + (long)row * D_MODEL;
  const float* yr = y + (long)row * D_MODEL;

  float v0 = xr[tid] + yr[tid];
  float v1 = xr[tid + 256] + yr[tid + 256];

  float s = v0 + v1;
#pragma unroll
  for (int off = 1; off < 64; off <<= 1) s += __shfl_xor(s, off);
  if ((tid & 63) == 0) red[tid >> 6] = s;
  __syncthreads();
  const float mean = (red[0] + red[1] + red[2] + red[3]) * (1.0f / D_MODEL);

  float d0 = v0 - mean, d1 = v1 - mean;
  float vs = d0 * d0 + d1 * d1;
#pragma unroll
  for (int off = 1; off < 64; off <<= 1) vs += __shfl_xor(vs, off);
  __syncthreads();
  if ((tid & 63) == 0) red[tid >> 6] = vs;
  __syncthreads();
  const float var = (red[0] + red[1] + red[2] + red[3]) * (1.0f / D_MODEL);
  const float rn = rsqrtf(var + 1e-6f);
  xr[tid] = d0 * rn;
  xr[tid + 256] = d1 * rn;
}

// ---------------------------------------------------------------------------
extern "C" void kernel_launch(void* const* d_in, const int* in_sizes, int n_in,
                              void* d_out, int out_size, void* d_ws, size_t ws_size,
                              hipStream_t stream) {
  const int* input_ids   = (const int*)d_in[0];
  const int* dec_ids     = (const int*)d_in[1];
  const float* dict      = (const float*)d_in[2];
  const float* mh_input  = (const float*)d_in[3];
  const float* wo_input  = (const float*)d_in[4];
  const float* mh_masked = (const float*)d_in[5];
  const float* wo_masked = (const float*)d_in[6];
  const float* mh_output = (const float*)d_in[7];
  const float* wo_output = (const float*)d_in[8];
  const float* ff_in_w1  = (const float*)d_in[9];
  const float* ff_in_w2  = (const float*)d_in[10];
  const float* ff_out_w1 = (const float*)d_in[11];
  const float* ff_out_w2 = (const float*)d_in[12];
  const float* last_lin  = (const float*)d_in[13];
  float* out = (float*)d_out;

  // workspace layout (floats)
  float* ws  = (float*)d_ws;
  float* enc = ws;                              // 2048*512
  float* dec = enc + ENC_LEN * D_MODEL;         // 1024*512
  float* qkv = dec + DEC_LEN * D_MODEL;         // 2048*1536 region
  float* att = qkv + (long)ENC_LEN * 3 * D_MODEL;  // 2048*512
  float* prj = att + ENC_LEN * D_MODEL;         // 2048*512
  float* hid = prj + ENC_LEN * D_MODEL;         // 2048*2048
  float* wend = hid + (long)ENC_LEN * D_FF;     // = ws + 11,010,048
  // optional hoisted cross-attn K/V: 6 * 2048 * 1024 floats
  float* kvbuf = wend;
  const size_t base_floats = 11010048;
  const size_t kv_floats = (size_t)N_LAYERS * ENC_LEN * 2 * D_MODEL;  // 12,582,912
  const bool hoist_kv = ws_size >= (base_floats + kv_floats) * sizeof(float);

  auto gemm = [&](const float* A, int lda, const float* B, int ldb,
                  float* C, int ldc, int M, int N, int K, bool relu) {
    dim3 g((N + 63) / 64, M / 64), b(256);
    if (relu)
      gemm_kernel<1><<<g, b, 0, stream>>>(A, lda, B, ldb, C, ldc, N, K);
    else
      gemm_kernel<0><<<g, b, 0, stream>>>(A, lda, B, ldb, C, ldc, N, K);
  };
  auto gemm128 = [&](const float* A, int lda, const float* B, int ldb,
                     float* C, int ldc, int M, int N, int K, bool relu,
                     int batch, long sB, long sC) {
    dim3 g(M / 128, (N + 127) / 128, batch), b(256);
    if (relu)
      gemm128_kernel<1><<<g, b, 0, stream>>>(A, lda, B, ldb, C, ldc, N, K, sB, sC);
    else
      gemm128_kernel<0><<<g, b, 0, stream>>>(A, lda, B, ldb, C, ldc, N, K, sB, sC);
  };

  // ===== Encoder =====
  embed_pe_kernel<<<ENC_LEN, D_MODEL, 0, stream>>>(input_ids, dict, enc);
  for (int l = 0; l < N_LAYERS; ++l) {
    const float* W = mh_input + (long)l * D_MODEL * 3 * D_MODEL;
    gemm128(enc, D_MODEL, W, 3 * D_MODEL, qkv, 3 * D_MODEL,
            ENC_LEN, 3 * D_MODEL, D_MODEL, false, 1, 0, 0);
    flash_attn_kernel<0><<<dim3(ENC_LEN / 64, N_HEADS), 256, 0, stream>>>(
        qkv, 3 * D_MODEL, qkv + D_MODEL, 3 * D_MODEL, qkv + 2 * D_MODEL,
        3 * D_MODEL, att, D_MODEL, ENC_LEN);
    gemm(att, D_MODEL, wo_input + (long)l * D_MODEL * D_MODEL, D_MODEL,
         prj, D_MODEL, ENC_LEN, D_MODEL, D_MODEL, false);
    add_norm_kernel<<<ENC_LEN, 256, 0, stream>>>(enc, prj);
    gemm128(enc, D_MODEL, ff_in_w1 + (long)l * D_MODEL * D_FF, D_FF,
            hid, D_FF, ENC_LEN, D_FF, D_MODEL, true, 1, 0, 0);
    gemm(hid, D_FF, ff_in_w2 + (long)l * D_FF * D_MODEL, D_MODEL,
         prj, D_MODEL, ENC_LEN, D_MODEL, D_FF, false);
    add_norm_kernel<<<ENC_LEN, 256, 0, stream>>>(enc, prj);
  }

  // ===== Hoisted cross-attention K/V projections (enc is frozen now) =====
  // C_l[:, 0:512] = enc @ Wk_l ; C_l[:, 512:1024] = enc @ Wv_l
  if (hoist_kv) {
    gemm128(enc, D_MODEL, mh_output + D_MODEL, 3 * D_MODEL,
            kvbuf, 2 * D_MODEL, ENC_LEN, 2 * D_MODEL, D_MODEL, false,
            N_LAYERS, (long)D_MODEL * 3 * D_MODEL,
            (long)ENC_LEN * 2 * D_MODEL);
  }

  // ===== Decoder =====
  embed_pe_kernel<<<DEC_LEN, D_MODEL, 0, stream>>>(dec_ids, dict, dec);
  float* qb = qkv;                        // 1024*512
  float* kb = qkv + DEC_LEN * D_MODEL;    // 2048*512 (fallback only)
  float* vb = kb + ENC_LEN * D_MODEL;     // 2048*512 (fallback only)
  for (int l = 0; l < N_LAYERS; ++l) {
    // masked self-attention
    const float* Wm = mh_masked + (long)l * D_MODEL * 3 * D_MODEL;
    gemm(dec, D_MODEL, Wm, 3 * D_MODEL, qkv, 3 * D_MODEL,
         DEC_LEN, 3 * D_MODEL, D_MODEL, false);
    flash_attn_kernel<1><<<dim3(DEC_LEN / 64, N_HEADS), 256, 0, stream>>>(
        qkv, 3 * D_MODEL, qkv + D_MODEL, 3 * D_MODEL, qkv + 2 * D_MODEL,
        3 * D_MODEL, att, D_MODEL, DEC_LEN);
    gemm(att, D_MODEL, wo_masked + (long)l * D_MODEL * D_MODEL, D_MODEL,
         prj, D_MODEL, DEC_LEN, D_MODEL, D_MODEL, false);
    add_norm_kernel<<<DEC_LEN, 256, 0, stream>>>(dec, prj);
    // cross-attention (q from dec, k/v from enc)
    const float* Wc = mh_output + (long)l * D_MODEL * 3 * D_MODEL;
    gemm(dec, D_MODEL, Wc, 3 * D_MODEL, qb, D_MODEL,
         DEC_LEN, D_MODEL, D_MODEL, false);
    if (hoist_kv) {
      const float* kvl = kvbuf + (long)l * ENC_LEN * 2 * D_MODEL;
      flash_attn_kernel<0><<<dim3(DEC_LEN / 64, N_HEADS), 256, 0, stream>>>(
          qb, D_MODEL, kvl, 2 * D_MODEL, kvl + D_MODEL, 2 * D_MODEL,
          att, D_MODEL, ENC_LEN);
    } else {
      gemm(enc, D_MODEL, Wc + D_MODEL, 3 * D_MODEL, kb, D_MODEL,
           ENC_LEN, D_MODEL, D_MODEL, false);
      gemm(enc, D_MODEL, Wc + 2 * D_MODEL, 3 * D_MODEL, vb, D_MODEL,
           ENC_LEN, D_MODEL, D_MODEL, false);
      flash_attn_kernel<0><<<dim3(DEC_LEN / 64, N_HEADS), 256, 0, stream>>>(
          qb, D_MODEL, kb, D_MODEL, vb, D_MODEL, att, D_MODEL, ENC_LEN);
    }
    gemm(att, D_MODEL, wo_output + (long)l * D_MODEL * D_MODEL, D_MODEL,
         prj, D_MODEL, DEC_LEN, D_MODEL, D_MODEL, false);
    add_norm_kernel<<<DEC_LEN, 256, 0, stream>>>(dec, prj);
    // FFN
    gemm(dec, D_MODEL, ff_out_w1 + (long)l * D_MODEL * D_FF, D_FF,
         hid, D_FF, DEC_LEN, D_FF, D_MODEL, true);
    gemm(hid, D_FF, ff_out_w2 + (long)l * D_FF * D_MODEL, D_MODEL,
         prj, D_MODEL, DEC_LEN, D_MODEL, D_FF, false);
    add_norm_kernel<<<DEC_LEN, 256, 0, stream>>>(dec, prj);
  }

  // ===== Final projection to vocab =====
  gemm128(dec, D_MODEL, last_lin, VOCAB, out, VOCAB,
          DEC_LEN, VOCAB, D_MODEL, false, 1, 0, 0);
}

// Round 3
// 8511.885 us; speedup vs baseline: 3.2769x; 1.2217x over previous
//
#include <hip/hip_runtime.h>
#include <hip/hip_bf16.h>
#include <math.h>

#define D_MODEL 512
#define N_HEADS 8
#define D_HEAD 64
#define N_LAYERS 6
#define D_FF 2048
#define VOCAB 50257
#define ENC_LEN 2048
#define DEC_LEN 1024

typedef short bf16x8 __attribute__((ext_vector_type(8)));
typedef float f32x4 __attribute__((ext_vector_type(4)));

// ---------------------------------------------------------------------------
// Embedding lookup + sinusoidal positional encoding
// ---------------------------------------------------------------------------
__global__ __launch_bounds__(512) void embed_pe_kernel(
    const int* __restrict__ ids, const float* __restrict__ dict,
    float* __restrict__ out) {
  int s = blockIdx.x;
  int d = threadIdx.x;
  float v = dict[(long)ids[s] * D_MODEL + d];
  float expo = (float)(d & ~1) / (float)D_MODEL;
  float ang = (float)s * expf(-expo * 9.210340371976184f);
  v += (d & 1) ? cosf(ang) : sinf(ang);
  out[(long)s * D_MODEL + d] = v;
}

// ---------------------------------------------------------------------------
// fp32 -> (bf16 hi, bf16 lo) split, packed two elements per u32.
// hi = truncate(x) (8 mantissa bits), lo = truncate(x - hi).
// Dropped Al*Bl term in the GEMM is <= 2^-16 relative.
// ---------------------------------------------------------------------------
__device__ inline void split2(float a, float b, unsigned int& h, unsigned int& l) {
  unsigned int ua = __float_as_uint(a), ub = __float_as_uint(b);
  unsigned int ha = ua & 0xFFFF0000u, hb = ub & 0xFFFF0000u;
  h = (ua >> 16) | hb;
  float la = a - __uint_as_float(ha);
  float lb = b - __uint_as_float(hb);
  l = (__float_as_uint(la) >> 16) | (__float_as_uint(lb) & 0xFFFF0000u);
}

// ---------------------------------------------------------------------------
// bf16x3 MFMA GEMM: C[M,N] = A[M,K] @ B[K,N] in near-fp32 precision.
// A = Ah+Al, B = Bh+Bl (bf16 splits); C = Ah@Bh + Ah@Bl + Al@Bh, fp32 acc.
// Tile 128x128, BK=32, 256 threads = 4 waves (2x2), each wave 64x64 out
// via 4x4 fragments of mfma_f32_16x16x32_bf16.
// LDS holds fragment-major tiles: [frag][lane][8 bf16] -> linear ds_read_b128.
// Fragment layout (gfx950 16x16x32 bf16):
//   A: lane l holds A[row = l&15][k = (l>>4)*8 + e], e=0..7
//   B: lane l holds B[k = (l>>4)*8 + e][col = l&15]
//   D: col = lane&15, row = (lane>>4)*4 + reg   [m89-verified]
// M % 128 == 0, K % 32 == 0, N arbitrary (guarded).
// Optional batching: B/C strided by blockIdx.z, A shared.
// ---------------------------------------------------------------------------
template <int RELU>
__global__ __launch_bounds__(256, 2) void gemm_mfma_kernel(
    const float* __restrict__ A, int lda,
    const float* __restrict__ B, int ldb,
    float* __restrict__ C, int ldc,
    int N, int K, long strideB, long strideC) {
  // fragment-major LDS: 8 fragments x 64 lanes x 16B each = 8KB per array
  __shared__ __align__(16) uint2 Ah2[8 * 128], Al2[8 * 128];
  __shared__ __align__(16) uint2 Bh2[8 * 128], Bl2[8 * 128];

  const int bm = blockIdx.x, bn = blockIdx.y;
  const int z = blockIdx.z;
  const float* Bb = B + (long)z * strideB;
  float* Cb = C + (long)z * strideC;

  const int tid = threadIdx.x;
  const int wave = tid >> 6;
  const int lane = tid & 63;
  const int wm = wave >> 1;   // 0..1
  const int wn = wave & 1;    // 0..1

  // --- staging maps ---
  // A: thread t handles row r = t>>1, k-half = (t&1)*16 (4 float4 along k)
  const int ar = tid >> 1;
  const int ah = (tid & 1) * 16;
  // B: thread t handles col n = (t&15) + (t>>5)*16, k-half = ((t>>4)&1)*16
  const int bnl = (tid & 15) + ((tid >> 5) << 4);
  const int bkh = ((tid >> 4) & 1) * 16;
  const int bcol = bn * 128 + bnl;
  const bool bok = (bcol < N);

  f32x4 acc[4][4];
#pragma unroll
  for (int i = 0; i < 4; ++i)
#pragma unroll
    for (int j = 0; j < 4; ++j) acc[i][j] = (f32x4)(0.0f);

  const float* Ap = A + (long)(bm * 128 + ar) * lda + ah;
  const float* Bp = Bb + (long)bkh * ldb + bcol;

  for (int k0 = 0; k0 < K; k0 += 32) {
    // ---- stage A 128x32 (hi/lo) ----
    {
      const int fi = ar >> 4;
      const int sb = ar & 15;
#pragma unroll
      for (int f = 0; f < 4; ++f) {
        float4 v = *(const float4*)(Ap + k0 + f * 4);
        int k4 = ah + f * 4;
        unsigned int hx, lx, hy, ly;
        split2(v.x, v.y, hx, lx);
        split2(v.z, v.w, hy, ly);
        int idx = fi * 128 + (sb + ((k4 >> 3) << 4)) * 2 + ((k4 & 7) >> 2);
        Ah2[idx] = make_uint2(hx, hy);
        Al2[idx] = make_uint2(lx, ly);
      }
    }
    // ---- stage B 32x128 (hi/lo), k-strided scalar loads ----
    {
      const int fj = bnl >> 4;
      const int sb = bnl & 15;
      const float* Bq = Bp + (long)k0 * ldb;
#pragma unroll
      for (int f = 0; f < 4; ++f) {
        int kb = bkh + f * 4;
        float b0 = 0.0f, b1 = 0.0f, b2 = 0.0f, b3 = 0.0f;
        if (bok) {
          const float* p = Bq + (long)(f * 4) * ldb;
          b0 = p[0];
          b1 = p[ldb];
          b2 = p[2 * ldb];
          b3 = p[3 * ldb];
        }
        unsigned int hx, lx, hy, ly;
        split2(b0, b1, hx, lx);
        split2(b2, b3, hy, ly);
        int idx = fj * 128 + (sb + ((kb >> 3) << 4)) * 2 + ((kb & 7) >> 2);
        Bh2[idx] = make_uint2(hx, hy);
        Bl2[idx] = make_uint2(lx, ly);
      }
    }
    __syncthreads();

    // ---- fragments + MFMA ----
    bf16x8 bh[4], bl[4];
#pragma unroll
    for (int n = 0; n < 4; ++n) {
      int fj = wn * 4 + n;
      bh[n] = *reinterpret_cast<const bf16x8*>(&Bh2[fj * 128 + lane * 2]);
      bl[n] = *reinterpret_cast<const bf16x8*>(&Bl2[fj * 128 + lane * 2]);
    }
#pragma unroll
    for (int m = 0; m < 4; ++m) {
      int fi = wm * 4 + m;
      bf16x8 a_h = *reinterpret_cast<const bf16x8*>(&Ah2[fi * 128 + lane * 2]);
      bf16x8 a_l = *reinterpret_cast<const bf16x8*>(&Al2[fi * 128 + lane * 2]);
#pragma unroll
      for (int n = 0; n < 4; ++n) {
        acc[m][n] = __builtin_amdgcn_mfma_f32_16x16x32_bf16(a_h, bl[n], acc[m][n], 0, 0, 0);
        acc[m][n] = __builtin_amdgcn_mfma_f32_16x16x32_bf16(a_l, bh[n], acc[m][n], 0, 0, 0);
        acc[m][n] = __builtin_amdgcn_mfma_f32_16x16x32_bf16(a_h, bh[n], acc[m][n], 0, 0, 0);
      }
    }
    __syncthreads();
  }

  // ---- epilogue: D mapping col=lane&15, row=(lane>>4)*4+reg ----
  const int rb = bm * 128 + wm * 64 + ((lane >> 4) << 2);
  const int cbase = bn * 128 + wn * 64 + (lane & 15);
#pragma unroll
  for (int m = 0; m < 4; ++m) {
#pragma unroll
    for (int n = 0; n < 4; ++n) {
      int col = cbase + n * 16;
      if (col < N) {
        float* Cp = Cb + (long)(rb + m * 16) * ldc + col;
#pragma unroll
        for (int r = 0; r < 4; ++r) {
          float v = acc[m][n][r];
          if (RELU) v = fmaxf(v, 0.0f);
          Cp[(long)r * ldc] = v;
        }
      }
    }
  }
}

// ---------------------------------------------------------------------------
// Flash-style fused attention, fp32 (unchanged).
// ---------------------------------------------------------------------------
template <int CAUSAL>
__global__ __launch_bounds__(256) void flash_attn_kernel(
    const float* __restrict__ Q, int ldq,
    const float* __restrict__ K, int ldk,
    const float* __restrict__ V, int ldv,
    float* __restrict__ O, int ldo,
    int Sk) {
  __shared__ float Qs[64][68];
  __shared__ float KV[64 * 68];
  __shared__ float Ps[64][68];

  const int qt = blockIdx.x;
  const int h = blockIdx.y;
  const int tid = threadIdx.x;
  const int tx = tid & 15;
  const int ty = tid >> 4;

  const int lrow = tid >> 2;
  const int lq = tid & 3;

  {
    const float* Qp = Q + (long)(qt * 64 + lrow) * ldq + h * D_HEAD + lq * 16;
#pragma unroll
    for (int f = 0; f < 4; ++f) {
      float4 v = *(const float4*)(Qp + f * 4);
      int d0 = lq * 16 + f * 4;
      Qs[d0 + 0][lrow] = v.x * 0.125f;
      Qs[d0 + 1][lrow] = v.y * 0.125f;
      Qs[d0 + 2][lrow] = v.z * 0.125f;
      Qs[d0 + 3][lrow] = v.w * 0.125f;
    }
  }

  float m[4], l[4], o[4][4];
#pragma unroll
  for (int i = 0; i < 4; ++i) {
    m[i] = -1e30f;
    l[i] = 0.0f;
#pragma unroll
    for (int j = 0; j < 4; ++j) o[i][j] = 0.0f;
  }
  __syncthreads();

  const int nkt = CAUSAL ? (qt + 1) : (Sk >> 6);
  for (int kt = 0; kt < nkt; ++kt) {
    {
      const float* Kp = K + (long)(kt * 64 + lrow) * ldk + h * D_HEAD + lq * 16;
#pragma unroll
      for (int f = 0; f < 4; ++f) {
        float4 v = *(const float4*)(Kp + f * 4);
        int d0 = lq * 16 + f * 4;
        KV[(d0 + 0) * 68 + lrow] = v.x;
        KV[(d0 + 1) * 68 + lrow] = v.y;
        KV[(d0 + 2) * 68 + lrow] = v.z;
        KV[(d0 + 3) * 68 + lrow] = v.w;
      }
    }
    __syncthreads();

    float s[4][4];
#pragma unroll
    for (int i = 0; i < 4; ++i)
#pragma unroll
      for (int j = 0; j < 4; ++j) s[i][j] = 0.0f;
#pragma unroll 8
    for (int kk = 0; kk < 64; ++kk) {
      float4 a = *(const float4*)&Qs[kk][ty * 4];
      float4 b = *(const float4*)&KV[kk * 68 + tx * 4];
      s[0][0] += a.x * b.x; s[0][1] += a.x * b.y;
      s[0][2] += a.x * b.z; s[0][3] += a.x * b.w;
      s[1][0] += a.y * b.x; s[1][1] += a.y * b.y;
      s[1][2] += a.y * b.z; s[1][3] += a.y * b.w;
      s[2][0] += a.z * b.x; s[2][1] += a.z * b.y;
      s[2][2] += a.z * b.z; s[2][3] += a.z * b.w;
      s[3][0] += a.w * b.x; s[3][1] += a.w * b.y;
      s[3][2] += a.w * b.z; s[3][3] += a.w * b.w;
    }

    if (CAUSAL && kt == qt) {
#pragma unroll
      for (int i = 0; i < 4; ++i)
#pragma unroll
        for (int j = 0; j < 4; ++j)
          if (tx * 4 + j > ty * 4 + i) s[i][j] = -1e30f;
    }

#pragma unroll
    for (int i = 0; i < 4; ++i) {
      float rm = fmaxf(fmaxf(s[i][0], s[i][1]), fmaxf(s[i][2], s[i][3]));
#pragma unroll
      for (int off = 1; off < 16; off <<= 1)
        rm = fmaxf(rm, __shfl_xor(rm, off));
      float mn = fmaxf(m[i], rm);
      float sc = __expf(m[i] - mn);
      float p0 = __expf(s[i][0] - mn);
      float p1 = __expf(s[i][1] - mn);
      float p2 = __expf(s[i][2] - mn);
      float p3 = __expf(s[i][3] - mn);
      float rs = (p0 + p1) + (p2 + p3);
#pragma unroll
      for (int off = 1; off < 16; off <<= 1) rs += __shfl_xor(rs, off);
      l[i] = l[i] * sc + rs;
      m[i] = mn;
      o[i][0] *= sc; o[i][1] *= sc; o[i][2] *= sc; o[i][3] *= sc;
      float4 pv = make_float4(p0, p1, p2, p3);
      *(float4*)&Ps[ty * 4 + i][tx * 4] = pv;
    }
    __syncthreads();

    {
      const float* Vp = V + (long)(kt * 64 + lrow) * ldv + h * D_HEAD + lq * 16;
#pragma unroll
      for (int f = 0; f < 4; ++f) {
        float4 v = *(const float4*)(Vp + f * 4);
        *(float4*)&KV[lrow * 64 + lq * 16 + f * 4] = v;
      }
    }
    __syncthreads();

#pragma unroll 4
    for (int kk0 = 0; kk0 < 64; kk0 += 4) {
      float a[4][4];
#pragma unroll
      for (int i = 0; i < 4; ++i)
        *(float4*)a[i] = *(const float4*)&Ps[ty * 4 + i][kk0];
#pragma unroll
      for (int u = 0; u < 4; ++u) {
        float4 b = *(const float4*)&KV[(kk0 + u) * 64 + tx * 4];
        o[0][0] += a[0][u] * b.x; o[0][1] += a[0][u] * b.y;
        o[0][2] += a[0][u] * b.z; o[0][3] += a[0][u] * b.w;
        o[1][0] += a[1][u] * b.x; o[1][1] += a[1][u] * b.y;
        o[1][2] += a[1][u] * b.z; o[1][3] += a[1][u] * b.w;
        o[2][0] += a[2][u] * b.x; o[2][1] += a[2][u] * b.y;
        o[2][2] += a[2][u] * b.z; o[2][3] += a[2][u] * b.w;
        o[3][0] += a[3][u] * b.x; o[3][1] += a[3][u] * b.y;
        o[3][2] += a[3][u] * b.z; o[3][3] += a[3][u] * b.w;
      }
    }
    __syncthreads();
  }

#pragma unroll
  for (int i = 0; i < 4; ++i) {
    float inv = 1.0f / l[i];
    float* Op = O + (long)(qt * 64 + ty * 4 + i) * ldo + h * D_HEAD + tx * 4;
    float4 ov = make_float4(o[i][0] * inv, o[i][1] * inv, o[i][2] * inv,
                            o[i][3] * inv);
    *(float4*)Op = ov;
  }
}

// ---------------------------------------------------------------------------
// x = layernorm(x + y)
// ---------------------------------------------------------------------------
__global__ __launch_bounds__(256) void add_norm_kernel(
    float* __restrict__ x, const float* __restrict__ y) {
  __shared__ float red[4];
  const int row = blockIdx.x;
  const int tid = threadIdx.x;
  float* xr = x + (long)row * D_MODEL;
  const float* yr = y + (long)row * D_MODEL;

  float v0 = xr[tid] + yr[tid];
  float v1 = xr[tid + 256] + yr[tid + 256];

  float s = v0 + v1;
#pragma unroll
  for (int off = 1; off < 64; off <<= 1) s += __shfl_xor(s, off);
  if ((tid & 63) == 0) red[tid >> 6] = s;
  __syncthreads();
  const float mean = (red[0] + red[1] + red[2] + red[3]) * (1.0f / D_MODEL);

  float d0 = v0 - mean, d1 = v1 - mean;
  float vs = d0 * d0 + d1 * d1;
#pragma unroll
  for (int off = 1; off < 64; off <<= 1) vs += __shfl_xor(vs, off);
  __syncthreads();
  if ((tid & 63) == 0) red[tid >> 6] = vs;
  __syncthreads();
  const float var = (red[0] + red[1] + red[2] + red[3]) * (1.0f / D_MODEL);
  const float rn = rsqrtf(var + 1e-6f);
  xr[tid] = d0 * rn;
  xr[tid + 256] = d1 * rn;
}

// ---------------------------------------------------------------------------
extern "C" void kernel_launch(void* const* d_in, const int* in_sizes, int n_in,
                              void* d_out, int out_size, void* d_ws, size_t ws_size,
                              hipStream_t stream) {
  const int* input_ids   = (const int*)d_in[0];
  const int* dec_ids     = (const int*)d_in[1];
  const float* dict      = (const float*)d_in[2];
  const float* mh_input  = (const float*)d_in[3];
  const float* wo_input  = (const float*)d_in[4];
  const float* mh_masked = (const float*)d_in[5];
  const float* wo_masked = (const float*)d_in[6];
  const float* mh_output = (const float*)d_in[7];
  const float* wo_output = (const float*)d_in[8];
  const float* ff_in_w1  = (const float*)d_in[9];
  const float* ff_in_w2  = (const float*)d_in[10];
  const float* ff_out_w1 = (const float*)d_in[11];
  const float* ff_out_w2 = (const float*)d_in[12];
  const float* last_lin  = (const float*)d_in[13];
  float* out = (float*)d_out;

  // workspace layout (floats)
  float* ws  = (float*)d_ws;
  float* enc = ws;                              // 2048*512
  float* dec = enc + ENC_LEN * D_MODEL;         // 1024*512
  float* qkv = dec + DEC_LEN * D_MODEL;         // 2048*1536 region
  float* att = qkv + (long)ENC_LEN * 3 * D_MODEL;  // 2048*512
  float* prj = att + ENC_LEN * D_MODEL;         // 2048*512
  float* hid = prj + ENC_LEN * D_MODEL;         // 2048*2048
  float* wend = hid + (long)ENC_LEN * D_FF;     // = ws + 11,010,048
  float* kvbuf = wend;
  const size_t base_floats = 11010048;
  const size_t kv_floats = (size_t)N_LAYERS * ENC_LEN * 2 * D_MODEL;  // 12,582,912
  const bool hoist_kv = ws_size >= (base_floats + kv_floats) * sizeof(float);

  // bf16x3 MFMA GEMM for everything: M%128==0, K%32==0, N guarded
  auto G = [&](const float* A, int lda, const float* B, int ldb,
               float* C, int ldc, int M, int N, int K, bool relu,
               int batch, long sB, long sC) {
    dim3 g(M / 128, (N + 127) / 128, batch), b(256);
    if (relu)
      gemm_mfma_kernel<1><<<g, b, 0, stream>>>(A, lda, B, ldb, C, ldc, N, K, sB, sC);
    else
      gemm_mfma_kernel<0><<<g, b, 0, stream>>>(A, lda, B, ldb, C, ldc, N, K, sB, sC);
  };

  // ===== Encoder =====
  embed_pe_kernel<<<ENC_LEN, D_MODEL, 0, stream>>>(input_ids, dict, enc);
  for (int l = 0; l < N_LAYERS; ++l) {
    const float* W = mh_input + (long)l * D_MODEL * 3 * D_MODEL;
    G(enc, D_MODEL, W, 3 * D_MODEL, qkv, 3 * D_MODEL,
      ENC_LEN, 3 * D_MODEL, D_MODEL, false, 1, 0, 0);
    flash_attn_kernel<0><<<dim3(ENC_LEN / 64, N_HEADS), 256, 0, stream>>>(
        qkv, 3 * D_MODEL, qkv + D_MODEL, 3 * D_MODEL, qkv + 2 * D_MODEL,
        3 * D_MODEL, att, D_MODEL, ENC_LEN);
    G(att, D_MODEL, wo_input + (long)l * D_MODEL * D_MODEL, D_MODEL,
      prj, D_MODEL, ENC_LEN, D_MODEL, D_MODEL, false, 1, 0, 0);
    add_norm_kernel<<<ENC_LEN, 256, 0, stream>>>(enc, prj);
    G(enc, D_MODEL, ff_in_w1 + (long)l * D_MODEL * D_FF, D_FF,
      hid, D_FF, ENC_LEN, D_FF, D_MODEL, true, 1, 0, 0);
    G(hid, D_FF, ff_in_w2 + (long)l * D_FF * D_MODEL, D_MODEL,
      prj, D_MODEL, ENC_LEN, D_MODEL, D_FF, false, 1, 0, 0);
    add_norm_kernel<<<ENC_LEN, 256, 0, stream>>>(enc, prj);
  }

  // ===== Hoisted cross-attention K/V projections (enc frozen) =====
  if (hoist_kv) {
    G(enc, D_MODEL, mh_output + D_MODEL, 3 * D_MODEL,
      kvbuf, 2 * D_MODEL, ENC_LEN, 2 * D_MODEL, D_MODEL, false,
      N_LAYERS, (long)D_MODEL * 3 * D_MODEL, (long)ENC_LEN * 2 * D_MODEL);
  }

  // ===== Decoder =====
  embed_pe_kernel<<<DEC_LEN, D_MODEL, 0, stream>>>(dec_ids, dict, dec);
  float* qb = qkv;                        // 1024*512
  float* kb = qkv + DEC_LEN * D_MODEL;    // fallback only
  float* vb = kb + ENC_LEN * D_MODEL;     // fallback only
  for (int l = 0; l < N_LAYERS; ++l) {
    // masked self-attention
    const float* Wm = mh_masked + (long)l * D_MODEL * 3 * D_MODEL;
    G(dec, D_MODEL, Wm, 3 * D_MODEL, qkv, 3 * D_MODEL,
      DEC_LEN, 3 * D_MODEL, D_MODEL, false, 1, 0, 0);
    flash_attn_kernel<1><<<dim3(DEC_LEN / 64, N_HEADS), 256, 0, stream>>>(
        qkv, 3 * D_MODEL, qkv + D_MODEL, 3 * D_MODEL, qkv + 2 * D_MODEL,
        3 * D_MODEL, att, D_MODEL, DEC_LEN);
    G(att, D_MODEL, wo_masked + (long)l * D_MODEL * D_MODEL, D_MODEL,
      prj, D_MODEL, DEC_LEN, D_MODEL, D_MODEL, false, 1, 0, 0);
    add_norm_kernel<<<DEC_LEN, 256, 0, stream>>>(dec, prj);
    // cross-attention (q from dec, k/v from enc)
    const float* Wc = mh_output + (long)l * D_MODEL * 3 * D_MODEL;
    G(dec, D_MODEL, Wc, 3 * D_MODEL, qb, D_MODEL,
      DEC_LEN, D_MODEL, D_MODEL, false, 1, 0, 0);
    if (hoist_kv) {
      const float* kvl = kvbuf + (long)l * ENC_LEN * 2 * D_MODEL;
      flash_attn_kernel<0><<<dim3(DEC_LEN / 64, N_HEADS), 256, 0, stream>>>(
          qb, D_MODEL, kvl, 2 * D_MODEL, kvl + D_MODEL, 2 * D_MODEL,
          att, D_MODEL, ENC_LEN);
    } else {
      G(enc, D_MODEL, Wc + D_MODEL, 3 * D_MODEL, kb, D_MODEL,
        ENC_LEN, D_MODEL, D_MODEL, false, 1, 0, 0);
      G(enc, D_MODEL, Wc + 2 * D_MODEL, 3 * D_MODEL, vb, D_MODEL,
        ENC_LEN, D_MODEL, D_MODEL, false, 1, 0, 0);
      flash_attn_kernel<0><<<dim3(DEC_LEN / 64, N_HEADS), 256, 0, stream>>>(
          qb, D_MODEL, kb, D_MODEL, vb, D_MODEL, att, D_MODEL, ENC_LEN);
    }
    G(att, D_MODEL, wo_output + (long)l * D_MODEL * D_MODEL, D_MODEL,
      prj, D_MODEL, DEC_LEN, D_MODEL, D_MODEL, false, 1, 0, 0);
    add_norm_kernel<<<DEC_LEN, 256, 0, stream>>>(dec, prj);
    // FFN
    G(dec, D_MODEL, ff_out_w1 + (long)l * D_MODEL * D_FF, D_FF,
      hid, D_FF, DEC_LEN, D_FF, D_MODEL, true, 1, 0, 0);
    G(hid, D_FF, ff_out_w2 + (long)l * D_FF * D_MODEL, D_MODEL,
      prj, D_MODEL, DEC_LEN, D_MODEL, D_FF, false, 1, 0, 0);
    add_norm_kernel<<<DEC_LEN, 256, 0, stream>>>(dec, prj);
  }

  // ===== Final projection to vocab =====
  G(dec, D_MODEL, last_lin, VOCAB, out, VOCAB,
    DEC_LEN, VOCAB, D_MODEL, false, 1, 0, 0);
}

// Round 4
// 5642.754 us; speedup vs baseline: 4.9431x; 1.5085x over previous
//
#include <hip/hip_runtime.h>
#include <hip/hip_bf16.h>
#include <math.h>

#define D_MODEL 512
#define N_HEADS 8
#define D_HEAD 64
#define N_LAYERS 6
#define D_FF 2048
#define VOCAB 50257
#define ENC_LEN 2048
#define DEC_LEN 1024

typedef short bf16x8 __attribute__((ext_vector_type(8)));
typedef float f32x4 __attribute__((ext_vector_type(4)));
typedef unsigned short u16;

// ---------------------------------------------------------------------------
// Embedding lookup + sinusoidal positional encoding
// ---------------------------------------------------------------------------
__global__ __launch_bounds__(512) void embed_pe_kernel(
    const int* __restrict__ ids, const float* __restrict__ dict,
    float* __restrict__ out) {
  int s = blockIdx.x;
  int d = threadIdx.x;
  float v = dict[(long)ids[s] * D_MODEL + d];
  float expo = (float)(d & ~1) / (float)D_MODEL;
  float ang = (float)s * expf(-expo * 9.210340371976184f);
  v += (d & 1) ? cosf(ang) : sinf(ang);
  out[(long)s * D_MODEL + d] = v;
}

// ---------------------------------------------------------------------------
// fp32 -> (bf16 hi, bf16 lo) split, packed two elements per u32.
// hi = truncate(x), lo = truncate(x - hi). Same math in pack + GEMM paths.
// ---------------------------------------------------------------------------
__device__ inline void split2(float a, float b, unsigned int& h, unsigned int& l) {
  unsigned int ua = __float_as_uint(a), ub = __float_as_uint(b);
  unsigned int ha = ua & 0xFFFF0000u, hb = ub & 0xFFFF0000u;
  h = (ua >> 16) | hb;
  float la = a - __uint_as_float(ha);
  float lb = b - __uint_as_float(hb);
  l = (__float_as_uint(la) >> 16) | (__float_as_uint(lb) & 0xFFFF0000u);
}

// ---------------------------------------------------------------------------
// Weight pre-pack: B[K][N] fp32 (ldb, optional z-batch) -> fragment-major
// bf16 hi/lo. Fragment = 16 cols x 32 k rows for mfma_f32_16x16x32_bf16 B:
//   lane l holds B[k = kb*32 + (l>>4)*8 + e][col = nb*16 + (l&15)], e=0..7.
// Packed address: ((z*fragZ + kb*NBLKp + nb) * 64 + lane) * 8 ushorts.
// Cols >= N zero-filled; NBLKp is NBLK rounded up to x8 so the GEMM needs
// no bounds checks on B loads.
// grid: (K/32, ceil(NBLKp/4), Z), block 256 (4 waves, one fragment each).
// ---------------------------------------------------------------------------
__global__ __launch_bounds__(256) void pack_b_kernel(
    const float* __restrict__ src, int ldb, int K, int N, long srcZ,
    u16* __restrict__ dh, u16* __restrict__ dl, int NBLKp, long fragZ) {
  const int kb = blockIdx.x;
  const int nb = blockIdx.y * 4 + (threadIdx.x >> 6);
  const int z = blockIdx.z;
  if (nb >= NBLKp) return;
  const int lane = threadIdx.x & 63;
  const int col = nb * 16 + (lane & 15);
  const int krow = kb * 32 + (lane >> 4) * 8;
  const float* s = src + (long)z * srcZ;
  unsigned int hw[4], lw[4];
#pragma unroll
  for (int p = 0; p < 4; ++p) {
    float v0 = 0.0f, v1 = 0.0f;
    if (col < N) {
      v0 = s[(long)(krow + p * 2) * ldb + col];
      v1 = s[(long)(krow + p * 2 + 1) * ldb + col];
    }
    split2(v0, v1, hw[p], lw[p]);
  }
  long off = ((long)z * fragZ + (long)kb * NBLKp + nb) * 512 + lane * 8;
  *(uint4*)(dh + off) = make_uint4(hw[0], hw[1], hw[2], hw[3]);
  *(uint4*)(dl + off) = make_uint4(lw[0], lw[1], lw[2], lw[3]);
}

// ---------------------------------------------------------------------------
// bf16x3 MFMA GEMM with PACKED B: C = A @ B, near-fp32 precision.
// Tile 128x128, BK=32, 4 waves (2x2). B fragments load straight from the
// packed global buffers to VGPR (coalesced 16B/lane, no LDS, no guards).
// A staged fp32->hi/lo through LDS (shared across the 2 wn waves).
// M % 128 == 0, K % 32 == 0. nblk0 = column-slice offset in fragments.
// ---------------------------------------------------------------------------
template <int RELU>
__global__ __launch_bounds__(256, 2) void gemm_mfma_pk(
    const float* __restrict__ A, int lda,
    const u16* __restrict__ Bh, const u16* __restrict__ Bl,
    float* __restrict__ C, int ldc,
    int N, int K, int NBLK, int nblk0, long fragZ, long strideC) {
  __shared__ __align__(16) uint2 Ah2[8 * 128], Al2[8 * 128];

  const int bm = blockIdx.x, bn = blockIdx.y;
  const int z = blockIdx.z;
  const u16* BhZ = Bh + (long)z * fragZ * 512;
  const u16* BlZ = Bl + (long)z * fragZ * 512;
  float* Cb = C + (long)z * strideC;

  const int tid = threadIdx.x;
  const int wave = tid >> 6;
  const int lane = tid & 63;
  const int wm = wave >> 1;
  const int wn = wave & 1;

  // A staging map: thread t -> row ar = t>>1, k-half (t&1)*16, 4 float4
  const int ar = tid >> 1;
  const int ah = (tid & 1) * 16;
  const int fi = ar >> 4, sb = ar & 15;
  const float* Ap = A + (long)(bm * 128 + ar) * lda + ah;

  const long nb0 = (long)nblk0 + (long)bn * 8 + wn * 4;

  f32x4 acc[4][4];
#pragma unroll
  for (int i = 0; i < 4; ++i)
#pragma unroll
    for (int j = 0; j < 4; ++j) acc[i][j] = (f32x4)(0.0f);

  for (int k0 = 0, kb = 0; k0 < K; k0 += 32, ++kb) {
    // ---- B fragments: global -> VGPR, issued first to hide latency ----
    bf16x8 bh[4], bl[4];
#pragma unroll
    for (int n = 0; n < 4; ++n) {
      long off = ((long)kb * NBLK + nb0 + n) * 512 + lane * 8;
      bh[n] = *reinterpret_cast<const bf16x8*>(BhZ + off);
      bl[n] = *reinterpret_cast<const bf16x8*>(BlZ + off);
    }
    // ---- stage A 128x32 (hi/lo) ----
#pragma unroll
    for (int f = 0; f < 4; ++f) {
      float4 v = *(const float4*)(Ap + k0 + f * 4);
      int k4 = ah + f * 4;
      unsigned int hx, lx, hy, ly;
      split2(v.x, v.y, hx, lx);
      split2(v.z, v.w, hy, ly);
      int idx = fi * 128 + (sb + ((k4 >> 3) << 4)) * 2 + ((k4 & 7) >> 2);
      Ah2[idx] = make_uint2(hx, hy);
      Al2[idx] = make_uint2(lx, ly);
    }
    __syncthreads();

#pragma unroll
    for (int m = 0; m < 4; ++m) {
      int fim = wm * 4 + m;
      bf16x8 a_h = *reinterpret_cast<const bf16x8*>(&Ah2[fim * 128 + lane * 2]);
      bf16x8 a_l = *reinterpret_cast<const bf16x8*>(&Al2[fim * 128 + lane * 2]);
#pragma unroll
      for (int n = 0; n < 4; ++n) {
        acc[m][n] = __builtin_amdgcn_mfma_f32_16x16x32_bf16(a_h, bl[n], acc[m][n], 0, 0, 0);
        acc[m][n] = __builtin_amdgcn_mfma_f32_16x16x32_bf16(a_l, bh[n], acc[m][n], 0, 0, 0);
        acc[m][n] = __builtin_amdgcn_mfma_f32_16x16x32_bf16(a_h, bh[n], acc[m][n], 0, 0, 0);
      }
    }
    __syncthreads();
  }

  const int rb = bm * 128 + wm * 64 + ((lane >> 4) << 2);
  const int cbase = bn * 128 + wn * 64 + (lane & 15);
#pragma unroll
  for (int m = 0; m < 4; ++m) {
#pragma unroll
    for (int n = 0; n < 4; ++n) {
      int col = cbase + n * 16;
      if (col < N) {
        float* Cp = Cb + (long)(rb + m * 16) * ldc + col;
#pragma unroll
        for (int r = 0; r < 4; ++r) {
          float v = acc[m][n][r];
          if (RELU) v = fmaxf(v, 0.0f);
          Cp[(long)r * ldc] = v;
        }
      }
    }
  }
}

// ---------------------------------------------------------------------------
// bf16x3 MFMA GEMM, unpacked B (fallback when workspace too small). R3 code.
// ---------------------------------------------------------------------------
template <int RELU>
__global__ __launch_bounds__(256, 2) void gemm_mfma_kernel(
    const float* __restrict__ A, int lda,
    const float* __restrict__ B, int ldb,
    float* __restrict__ C, int ldc,
    int N, int K, long strideB, long strideC) {
  __shared__ __align__(16) uint2 Ah2[8 * 128], Al2[8 * 128];
  __shared__ __align__(16) uint2 Bh2[8 * 128], Bl2[8 * 128];

  const int bm = blockIdx.x, bn = blockIdx.y;
  const int z = blockIdx.z;
  const float* Bb = B + (long)z * strideB;
  float* Cb = C + (long)z * strideC;

  const int tid = threadIdx.x;
  const int wave = tid >> 6;
  const int lane = tid & 63;
  const int wm = wave >> 1;
  const int wn = wave & 1;

  const int ar = tid >> 1;
  const int ah = (tid & 1) * 16;
  const int bnl = (tid & 15) + ((tid >> 5) << 4);
  const int bkh = ((tid >> 4) & 1) * 16;
  const int bcol = bn * 128 + bnl;
  const bool bok = (bcol < N);

  f32x4 acc[4][4];
#pragma unroll
  for (int i = 0; i < 4; ++i)
#pragma unroll
    for (int j = 0; j < 4; ++j) acc[i][j] = (f32x4)(0.0f);

  const float* Ap = A + (long)(bm * 128 + ar) * lda + ah;
  const float* Bp = Bb + (long)bkh * ldb + bcol;

  for (int k0 = 0; k0 < K; k0 += 32) {
    {
      const int fi = ar >> 4;
      const int sb = ar & 15;
#pragma unroll
      for (int f = 0; f < 4; ++f) {
        float4 v = *(const float4*)(Ap + k0 + f * 4);
        int k4 = ah + f * 4;
        unsigned int hx, lx, hy, ly;
        split2(v.x, v.y, hx, lx);
        split2(v.z, v.w, hy, ly);
        int idx = fi * 128 + (sb + ((k4 >> 3) << 4)) * 2 + ((k4 & 7) >> 2);
        Ah2[idx] = make_uint2(hx, hy);
        Al2[idx] = make_uint2(lx, ly);
      }
    }
    {
      const int fj = bnl >> 4;
      const int sb = bnl & 15;
      const float* Bq = Bp + (long)k0 * ldb;
#pragma unroll
      for (int f = 0; f < 4; ++f) {
        int kb = bkh + f * 4;
        float b0 = 0.0f, b1 = 0.0f, b2 = 0.0f, b3 = 0.0f;
        if (bok) {
          const float* p = Bq + (long)(f * 4) * ldb;
          b0 = p[0];
          b1 = p[ldb];
          b2 = p[2 * ldb];
          b3 = p[3 * ldb];
        }
        unsigned int hx, lx, hy, ly;
        split2(b0, b1, hx, lx);
        split2(b2, b3, hy, ly);
        int idx = fj * 128 + (sb + ((kb >> 3) << 4)) * 2 + ((kb & 7) >> 2);
        Bh2[idx] = make_uint2(hx, hy);
        Bl2[idx] = make_uint2(lx, ly);
      }
    }
    __syncthreads();

    bf16x8 bh[4], bl[4];
#pragma unroll
    for (int n = 0; n < 4; ++n) {
      int fj = wn * 4 + n;
      bh[n] = *reinterpret_cast<const bf16x8*>(&Bh2[fj * 128 + lane * 2]);
      bl[n] = *reinterpret_cast<const bf16x8*>(&Bl2[fj * 128 + lane * 2]);
    }
#pragma unroll
    for (int m = 0; m < 4; ++m) {
      int fi = wm * 4 + m;
      bf16x8 a_h = *reinterpret_cast<const bf16x8*>(&Ah2[fi * 128 + lane * 2]);
      bf16x8 a_l = *reinterpret_cast<const bf16x8*>(&Al2[fi * 128 + lane * 2]);
#pragma unroll
      for (int n = 0; n < 4; ++n) {
        acc[m][n] = __builtin_amdgcn_mfma_f32_16x16x32_bf16(a_h, bl[n], acc[m][n], 0, 0, 0);
        acc[m][n] = __builtin_amdgcn_mfma_f32_16x16x32_bf16(a_l, bh[n], acc[m][n], 0, 0, 0);
        acc[m][n] = __builtin_amdgcn_mfma_f32_16x16x32_bf16(a_h, bh[n], acc[m][n], 0, 0, 0);
      }
    }
    __syncthreads();
  }

  const int rb = bm * 128 + wm * 64 + ((lane >> 4) << 2);
  const int cbase = bn * 128 + wn * 64 + (lane & 15);
#pragma unroll
  for (int m = 0; m < 4; ++m) {
#pragma unroll
    for (int n = 0; n < 4; ++n) {
      int col = cbase + n * 16;
      if (col < N) {
        float* Cp = Cb + (long)(rb + m * 16) * ldc + col;
#pragma unroll
        for (int r = 0; r < 4; ++r) {
          float v = acc[m][n][r];
          if (RELU) v = fmaxf(v, 0.0f);
          Cp[(long)r * ldc] = v;
        }
      }
    }
  }
}

// ---------------------------------------------------------------------------
// Flash-style fused attention, fp32 (unchanged).
// ---------------------------------------------------------------------------
template <int CAUSAL>
__global__ __launch_bounds__(256) void flash_attn_kernel(
    const float* __restrict__ Q, int ldq,
    const float* __restrict__ K, int ldk,
    const float* __restrict__ V, int ldv,
    float* __restrict__ O, int ldo,
    int Sk) {
  __shared__ float Qs[64][68];
  __shared__ float KV[64 * 68];
  __shared__ float Ps[64][68];

  const int qt = blockIdx.x;
  const int h = blockIdx.y;
  const int tid = threadIdx.x;
  const int tx = tid & 15;
  const int ty = tid >> 4;

  const int lrow = tid >> 2;
  const int lq = tid & 3;

  {
    const float* Qp = Q + (long)(qt * 64 + lrow) * ldq + h * D_HEAD + lq * 16;
#pragma unroll
    for (int f = 0; f < 4; ++f) {
      float4 v = *(const float4*)(Qp + f * 4);
      int d0 = lq * 16 + f * 4;
      Qs[d0 + 0][lrow] = v.x * 0.125f;
      Qs[d0 + 1][lrow] = v.y * 0.125f;
      Qs[d0 + 2][lrow] = v.z * 0.125f;
      Qs[d0 + 3][lrow] = v.w * 0.125f;
    }
  }

  float m[4], l[4], o[4][4];
#pragma unroll
  for (int i = 0; i < 4; ++i) {
    m[i] = -1e30f;
    l[i] = 0.0f;
#pragma unroll
    for (int j = 0; j < 4; ++j) o[i][j] = 0.0f;
  }
  __syncthreads();

  const int nkt = CAUSAL ? (qt + 1) : (Sk >> 6);
  for (int kt = 0; kt < nkt; ++kt) {
    {
      const float* Kp = K + (long)(kt * 64 + lrow) * ldk + h * D_HEAD + lq * 16;
#pragma unroll
      for (int f = 0; f < 4; ++f) {
        float4 v = *(const float4*)(Kp + f * 4);
        int d0 = lq * 16 + f * 4;
        KV[(d0 + 0) * 68 + lrow] = v.x;
        KV[(d0 + 1) * 68 + lrow] = v.y;
        KV[(d0 + 2) * 68 + lrow] = v.z;
        KV[(d0 + 3) * 68 + lrow] = v.w;
      }
    }
    __syncthreads();

    float s[4][4];
#pragma unroll
    for (int i = 0; i < 4; ++i)
#pragma unroll
      for (int j = 0; j < 4; ++j) s[i][j] = 0.0f;
#pragma unroll 8
    for (int kk = 0; kk < 64; ++kk) {
      float4 a = *(const float4*)&Qs[kk][ty * 4];
      float4 b = *(const float4*)&KV[kk * 68 + tx * 4];
      s[0][0] += a.x * b.x; s[0][1] += a.x * b.y;
      s[0][2] += a.x * b.z; s[0][3] += a.x * b.w;
      s[1][0] += a.y * b.x; s[1][1] += a.y * b.y;
      s[1][2] += a.y * b.z; s[1][3] += a.y * b.w;
      s[2][0] += a.z * b.x; s[2][1] += a.z * b.y;
      s[2][2] += a.z * b.z; s[2][3] += a.z * b.w;
      s[3][0] += a.w * b.x; s[3][1] += a.w * b.y;
      s[3][2] += a.w * b.z; s[3][3] += a.w * b.w;
    }

    if (CAUSAL && kt == qt) {
#pragma unroll
      for (int i = 0; i < 4; ++i)
#pragma unroll
        for (int j = 0; j < 4; ++j)
          if (tx * 4 + j > ty * 4 + i) s[i][j] = -1e30f;
    }

#pragma unroll
    for (int i = 0; i < 4; ++i) {
      float rm = fmaxf(fmaxf(s[i][0], s[i][1]), fmaxf(s[i][2], s[i][3]));
#pragma unroll
      for (int off = 1; off < 16; off <<= 1)
        rm = fmaxf(rm, __shfl_xor(rm, off));
      float mn = fmaxf(m[i], rm);
      float sc = __expf(m[i] - mn);
      float p0 = __expf(s[i][0] - mn);
      float p1 = __expf(s[i][1] - mn);
      float p2 = __expf(s[i][2] - mn);
      float p3 = __expf(s[i][3] - mn);
      float rs = (p0 + p1) + (p2 + p3);
#pragma unroll
      for (int off = 1; off < 16; off <<= 1) rs += __shfl_xor(rs, off);
      l[i] = l[i] * sc + rs;
      m[i] = mn;
      o[i][0] *= sc; o[i][1] *= sc; o[i][2] *= sc; o[i][3] *= sc;
      float4 pv = make_float4(p0, p1, p2, p3);
      *(float4*)&Ps[ty * 4 + i][tx * 4] = pv;
    }
    __syncthreads();

    {
      const float* Vp = V + (long)(kt * 64 + lrow) * ldv + h * D_HEAD + lq * 16;
#pragma unroll
      for (int f = 0; f < 4; ++f) {
        float4 v = *(const float4*)(Vp + f * 4);
        *(float4*)&KV[lrow * 64 + lq * 16 + f * 4] = v;
      }
    }
    __syncthreads();

#pragma unroll 4
    for (int kk0 = 0; kk0 < 64; kk0 += 4) {
      float a[4][4];
#pragma unroll
      for (int i = 0; i < 4; ++i)
        *(float4*)a[i] = *(const float4*)&Ps[ty * 4 + i][kk0];
#pragma unroll
      for (int u = 0; u < 4; ++u) {
        float4 b = *(const float4*)&KV[(kk0 + u) * 64 + tx * 4];
        o[0][0] += a[0][u] * b.x; o[0][1] += a[0][u] * b.y;
        o[0][2] += a[0][u] * b.z; o[0][3] += a[0][u] * b.w;
        o[1][0] += a[1][u] * b.x; o[1][1] += a[1][u] * b.y;
        o[1][2] += a[1][u] * b.z; o[1][3] += a[1][u] * b.w;
        o[2][0] += a[2][u] * b.x; o[2][1] += a[2][u] * b.y;
        o[2][2] += a[2][u] * b.z; o[2][3] += a[2][u] * b.w;
        o[3][0] += a[3][u] * b.x; o[3][1] += a[3][u] * b.y;
        o[3][2] += a[3][u] * b.z; o[3][3] += a[3][u] * b.w;
      }
    }
    __syncthreads();
  }

#pragma unroll
  for (int i = 0; i < 4; ++i) {
    float inv = 1.0f / l[i];
    float* Op = O + (long)(qt * 64 + ty * 4 + i) * ldo + h * D_HEAD + tx * 4;
    float4 ov = make_float4(o[i][0] * inv, o[i][1] * inv, o[i][2] * inv,
                            o[i][3] * inv);
    *(float4*)Op = ov;
  }
}

// ---------------------------------------------------------------------------
// x = layernorm(x + y)
// ---------------------------------------------------------------------------
__global__ __launch_bounds__(256) void add_norm_kernel(
    float* __restrict__ x, const float* __restrict__ y) {
  __shared__ float red[4];
  const int row = blockIdx.x;
  const int tid = threadIdx.x;
  float* xr = x + (long)row * D_MODEL;
  const float* yr = y + (long)row * D_MODEL;

  float v0 = xr[tid] + yr[tid];
  float v1 = xr[tid + 256] + yr[tid + 256];

  float s = v0 + v1;
#pragma unroll
  for (int off = 1; off < 64; off <<= 1) s += __shfl_xor(s, off);
  if ((tid & 63) == 0) red[tid >> 6] = s;
  __syncthreads();
  const float mean = (red[0] + red[1] + red[2] + red[3]) * (1.0f / D_MODEL);

  float d0 = v0 - mean, d1 = v1 - mean;
  float vs = d0 * d0 + d1 * d1;
#pragma unroll
  for (int off = 1; off < 64; off <<= 1) vs += __shfl_xor(vs, off);
  __syncthreads();
  if ((tid & 63) == 0) red[tid >> 6] = vs;
  __syncthreads();
  const float var = (red[0] + red[1] + red[2] + red[3]) * (1.0f / D_MODEL);
  const float rn = rsqrtf(var + 1e-6f);
  xr[tid] = d0 * rn;
  xr[tid + 256] = d1 * rn;
}

// ---------------------------------------------------------------------------
extern "C" void kernel_launch(void* const* d_in, const int* in_sizes, int n_in,
                              void* d_out, int out_size, void* d_ws, size_t ws_size,
                              hipStream_t stream) {
  const int* input_ids   = (const int*)d_in[0];
  const int* dec_ids     = (const int*)d_in[1];
  const float* dict      = (const float*)d_in[2];
  const float* mh_input  = (const float*)d_in[3];
  const float* wo_input  = (const float*)d_in[4];
  const float* mh_masked = (const float*)d_in[5];
  const float* wo_masked = (const float*)d_in[6];
  const float* mh_output = (const float*)d_in[7];
  const float* wo_output = (const float*)d_in[8];
  const float* ff_in_w1  = (const float*)d_in[9];
  const float* ff_in_w2  = (const float*)d_in[10];
  const float* ff_out_w1 = (const float*)d_in[11];
  const float* ff_out_w2 = (const float*)d_in[12];
  const float* last_lin  = (const float*)d_in[13];
  float* out = (float*)d_out;

  // ---- workspace: float regions ----
  float* ws  = (float*)d_ws;
  float* enc = ws;                                  // 2048*512
  float* dec = enc + ENC_LEN * D_MODEL;             // 1024*512
  float* qkv = dec + DEC_LEN * D_MODEL;             // 2048*1536
  float* att = qkv + (long)ENC_LEN * 3 * D_MODEL;   // 2048*512
  float* prj = att + ENC_LEN * D_MODEL;             // 2048*512
  float* hid = prj + ENC_LEN * D_MODEL;             // 2048*2048
  float* wend = hid + (long)ENC_LEN * D_FF;         // = ws + 11,010,048
  float* kvbuf = wend;
  const size_t base_floats = 11010048;
  const size_t kv_floats = (size_t)N_LAYERS * ENC_LEN * 2 * D_MODEL;
  const bool hoist_kv = ws_size >= (base_floats + kv_floats) * sizeof(float);

  // ---- bump allocator for packed weights ----
  size_t used = (base_floats + (hoist_kv ? kv_floats : 0)) * sizeof(float);
  used = (used + 255) & ~(size_t)255;
  auto alloc_us = [&](size_t n_ushort) -> u16* {
    size_t bytes = (n_ushort * 2 + 255) & ~(size_t)255;
    if (used + bytes > ws_size) return nullptr;
    u16* p = (u16*)((char*)d_ws + used);
    used += bytes;
    return p;
  };

  struct PK { u16* h; u16* l; int nblkp; long fragZ; };
  // Pack B[K][N] (Z-layered) into fragment layout; greedy: null if no room.
  auto packW = [&](const float* src, int ldb, int K, int N, int Z,
                   long srcZ) -> PK {
    int nblkp = (((N + 15) >> 4) + 7) & ~7;
    long fragZ = (long)(K / 32) * nblkp;
    size_t n_us = (size_t)Z * fragZ * 512;
    u16* h = alloc_us(n_us);
    u16* l = h ? alloc_us(n_us) : nullptr;
    if (!h || !l) return PK{nullptr, nullptr, 0, 0};
    dim3 g(K / 32, (nblkp + 3) / 4, Z), b(256);
    pack_b_kernel<<<g, b, 0, stream>>>(src, ldb, K, N, srcZ, h, l, nblkp, fragZ);
    return PK{h, l, nblkp, fragZ};
  };

  // priority order: biggest wins first
  PK pk_last   = packW(last_lin,  VOCAB,       D_MODEL, VOCAB,       1, 0);
  PK pk_ffin1  = packW(ff_in_w1,  D_FF,        D_MODEL, D_FF,        N_LAYERS, (long)D_MODEL * D_FF);
  PK pk_ffin2  = packW(ff_in_w2,  D_MODEL,     D_FF,    D_MODEL,     N_LAYERS, (long)D_FF * D_MODEL);
  PK pk_ffout1 = packW(ff_out_w1, D_FF,        D_MODEL, D_FF,        N_LAYERS, (long)D_MODEL * D_FF);
  PK pk_ffout2 = packW(ff_out_w2, D_MODEL,     D_FF,    D_MODEL,     N_LAYERS, (long)D_FF * D_MODEL);
  PK pk_mhin   = packW(mh_input,  3 * D_MODEL, D_MODEL, 3 * D_MODEL, N_LAYERS, (long)D_MODEL * 3 * D_MODEL);
  PK pk_mhmk   = packW(mh_masked, 3 * D_MODEL, D_MODEL, 3 * D_MODEL, N_LAYERS, (long)D_MODEL * 3 * D_MODEL);
  PK pk_mhout  = packW(mh_output, 3 * D_MODEL, D_MODEL, 3 * D_MODEL, N_LAYERS, (long)D_MODEL * 3 * D_MODEL);
  PK pk_woin   = packW(wo_input,  D_MODEL,     D_MODEL, D_MODEL,     N_LAYERS, (long)D_MODEL * D_MODEL);
  PK pk_womk   = packW(wo_masked, D_MODEL,     D_MODEL, D_MODEL,     N_LAYERS, (long)D_MODEL * D_MODEL);
  PK pk_woout  = packW(wo_output, D_MODEL,     D_MODEL, D_MODEL,     N_LAYERS, (long)D_MODEL * D_MODEL);

  // old-path GEMM (unpacked B)
  auto Gold = [&](const float* A, int lda, const float* B, int ldb,
                  float* C, int ldc, int M, int N, int K, bool relu,
                  int batch, long sB, long sC) {
    dim3 g(M / 128, (N + 127) / 128, batch), b(256);
    if (relu)
      gemm_mfma_kernel<1><<<g, b, 0, stream>>>(A, lda, B, ldb, C, ldc, N, K, sB, sC);
    else
      gemm_mfma_kernel<0><<<g, b, 0, stream>>>(A, lda, B, ldb, C, ldc, N, K, sB, sC);
  };
  // packed-B GEMM; layer picks the z-slice when batch==1
  auto Gpk = [&](const float* A, int lda, const PK& pk, int layer, int nblk0,
                 float* C, int ldc, int M, int N, int K, bool relu,
                 int batch, long sC) {
    dim3 g(M / 128, (N + 127) / 128, batch), b(256);
    const u16* ph = pk.h + (long)layer * pk.fragZ * 512;
    const u16* pl = pk.l + (long)layer * pk.fragZ * 512;
    long fz = (batch > 1) ? pk.fragZ : 0;
    if (relu)
      gemm_mfma_pk<1><<<g, b, 0, stream>>>(A, lda, ph, pl, C, ldc, N, K, pk.nblkp, nblk0, fz, sC);
    else
      gemm_mfma_pk<0><<<g, b, 0, stream>>>(A, lda, ph, pl, C, ldc, N, K, pk.nblkp, nblk0, fz, sC);
  };

  // ===== Encoder =====
  embed_pe_kernel<<<ENC_LEN, D_MODEL, 0, stream>>>(input_ids, dict, enc);
  for (int l = 0; l < N_LAYERS; ++l) {
    const float* W = mh_input + (long)l * D_MODEL * 3 * D_MODEL;
    if (pk_mhin.h)
      Gpk(enc, D_MODEL, pk_mhin, l, 0, qkv, 3 * D_MODEL,
          ENC_LEN, 3 * D_MODEL, D_MODEL, false, 1, 0);
    else
      Gold(enc, D_MODEL, W, 3 * D_MODEL, qkv, 3 * D_MODEL,
           ENC_LEN, 3 * D_MODEL, D_MODEL, false, 1, 0, 0);
    flash_attn_kernel<0><<<dim3(ENC_LEN / 64, N_HEADS), 256, 0, stream>>>(
        qkv, 3 * D_MODEL, qkv + D_MODEL, 3 * D_MODEL, qkv + 2 * D_MODEL,
        3 * D_MODEL, att, D_MODEL, ENC_LEN);
    if (pk_woin.h)
      Gpk(att, D_MODEL, pk_woin, l, 0, prj, D_MODEL,
          ENC_LEN, D_MODEL, D_MODEL, false, 1, 0);
    else
      Gold(att, D_MODEL, wo_input + (long)l * D_MODEL * D_MODEL, D_MODEL,
           prj, D_MODEL, ENC_LEN, D_MODEL, D_MODEL, false, 1, 0, 0);
    add_norm_kernel<<<ENC_LEN, 256, 0, stream>>>(enc, prj);
    if (pk_ffin1.h)
      Gpk(enc, D_MODEL, pk_ffin1, l, 0, hid, D_FF,
          ENC_LEN, D_FF, D_MODEL, true, 1, 0);
    else
      Gold(enc, D_MODEL, ff_in_w1 + (long)l * D_MODEL * D_FF, D_FF,
           hid, D_FF, ENC_LEN, D_FF, D_MODEL, true, 1, 0, 0);
    if (pk_ffin2.h)
      Gpk(hid, D_FF, pk_ffin2, l, 0, prj, D_MODEL,
          ENC_LEN, D_MODEL, D_FF, false, 1, 0);
    else
      Gold(hid, D_FF, ff_in_w2 + (long)l * D_FF * D_MODEL, D_MODEL,
           prj, D_MODEL, ENC_LEN, D_MODEL, D_FF, false, 1, 0, 0);
    add_norm_kernel<<<ENC_LEN, 256, 0, stream>>>(enc, prj);
  }

  // ===== Hoisted cross-attention K/V projections (enc frozen) =====
  if (hoist_kv) {
    if (pk_mhout.h)
      Gpk(enc, D_MODEL, pk_mhout, 0, 32, kvbuf, 2 * D_MODEL,
          ENC_LEN, 2 * D_MODEL, D_MODEL, false, N_LAYERS,
          (long)ENC_LEN * 2 * D_MODEL);
    else
      Gold(enc, D_MODEL, mh_output + D_MODEL, 3 * D_MODEL,
           kvbuf, 2 * D_MODEL, ENC_LEN, 2 * D_MODEL, D_MODEL, false,
           N_LAYERS, (long)D_MODEL * 3 * D_MODEL, (long)ENC_LEN * 2 * D_MODEL);
  }

  // ===== Decoder =====
  embed_pe_kernel<<<DEC_LEN, D_MODEL, 0, stream>>>(dec_ids, dict, dec);
  float* qb = qkv;
  float* kb = qkv + DEC_LEN * D_MODEL;
  float* vb = kb + ENC_LEN * D_MODEL;
  for (int l = 0; l < N_LAYERS; ++l) {
    const float* Wm = mh_masked + (long)l * D_MODEL * 3 * D_MODEL;
    if (pk_mhmk.h)
      Gpk(dec, D_MODEL, pk_mhmk, l, 0, qkv, 3 * D_MODEL,
          DEC_LEN, 3 * D_MODEL, D_MODEL, false, 1, 0);
    else
      Gold(dec, D_MODEL, Wm, 3 * D_MODEL, qkv, 3 * D_MODEL,
           DEC_LEN, 3 * D_MODEL, D_MODEL, false, 1, 0, 0);
    flash_attn_kernel<1><<<dim3(DEC_LEN / 64, N_HEADS), 256, 0, stream>>>(
        qkv, 3 * D_MODEL, qkv + D_MODEL, 3 * D_MODEL, qkv + 2 * D_MODEL,
        3 * D_MODEL, att, D_MODEL, DEC_LEN);
    if (pk_womk.h)
      Gpk(att, D_MODEL, pk_womk, l, 0, prj, D_MODEL,
          DEC_LEN, D_MODEL, D_MODEL, false, 1, 0);
    else
      Gold(att, D_MODEL, wo_masked + (long)l * D_MODEL * D_MODEL, D_MODEL,
           prj, D_MODEL, DEC_LEN, D_MODEL, D_MODEL, false, 1, 0, 0);
    add_norm_kernel<<<DEC_LEN, 256, 0, stream>>>(dec, prj);

    const float* Wc = mh_output + (long)l * D_MODEL * 3 * D_MODEL;
    if (pk_mhout.h)
      Gpk(dec, D_MODEL, pk_mhout, l, 0, qb, D_MODEL,
          DEC_LEN, D_MODEL, D_MODEL, false, 1, 0);
    else
      Gold(dec, D_MODEL, Wc, 3 * D_MODEL, qb, D_MODEL,
           DEC_LEN, D_MODEL, D_MODEL, false, 1, 0, 0);
    if (hoist_kv) {
      const float* kvl = kvbuf + (long)l * ENC_LEN * 2 * D_MODEL;
      flash_attn_kernel<0><<<dim3(DEC_LEN / 64, N_HEADS), 256, 0, stream>>>(
          qb, D_MODEL, kvl, 2 * D_MODEL, kvl + D_MODEL, 2 * D_MODEL,
          att, D_MODEL, ENC_LEN);
    } else {
      Gold(enc, D_MODEL, Wc + D_MODEL, 3 * D_MODEL, kb, D_MODEL,
           ENC_LEN, D_MODEL, D_MODEL, false, 1, 0, 0);
      Gold(enc, D_MODEL, Wc + 2 * D_MODEL, 3 * D_MODEL, vb, D_MODEL,
           ENC_LEN, D_MODEL, D_MODEL, false, 1, 0, 0);
      flash_attn_kernel<0><<<dim3(DEC_LEN / 64, N_HEADS), 256, 0, stream>>>(
          qb, D_MODEL, kb, D_MODEL, vb, D_MODEL, att, D_MODEL, ENC_LEN);
    }
    if (pk_woout.h)
      Gpk(att, D_MODEL, pk_woout, l, 0, prj, D_MODEL,
          DEC_LEN, D_MODEL, D_MODEL, false, 1, 0);
    else
      Gold(att, D_MODEL, wo_output + (long)l * D_MODEL * D_MODEL, D_MODEL,
           prj, D_MODEL, DEC_LEN, D_MODEL, D_MODEL, false, 1, 0, 0);
    add_norm_kernel<<<DEC_LEN, 256, 0, stream>>>(dec, prj);

    if (pk_ffout1.h)
      Gpk(dec, D_MODEL, pk_ffout1, l, 0, hid, D_FF,
          DEC_LEN, D_FF, D_MODEL, true, 1, 0);
    else
      Gold(dec, D_MODEL, ff_out_w1 + (long)l * D_MODEL * D_FF, D_FF,
           hid, D_FF, DEC_LEN, D_FF, D_MODEL, true, 1, 0, 0);
    if (pk_ffout2.h)
      Gpk(hid, D_FF, pk_ffout2, l, 0, prj, D_MODEL,
          DEC_LEN, D_MODEL, D_FF, false, 1, 0);
    else
      Gold(hid, D_FF, ff_out_w2 + (long)l * D_FF * D_MODEL, D_MODEL,
           prj, D_MODEL, DEC_LEN, D_MODEL, D_FF, false, 1, 0, 0);
    add_norm_kernel<<<DEC_LEN, 256, 0, stream>>>(dec, prj);
  }

  // ===== Final projection to vocab =====
  if (pk_last.h)
    Gpk(dec, D_MODEL, pk_last, 0, 0, out, VOCAB,
        DEC_LEN, VOCAB, D_MODEL, false, 1, 0);
  else
    Gold(dec, D_MODEL, last_lin, VOCAB, out, VOCAB,
         DEC_LEN, VOCAB, D_MODEL, false, 1, 0, 0);
}